// Round 2
// baseline (1914.387 us; speedup 1.0000x reference)
//
#include <hip/hip_runtime.h>
#include <hip/hip_bf16.h>

#define HID 128
#define NEG_SLOPE 0.2f
#define LN_EPS 1e-5f

// ---------- helpers ----------
__device__ __forceinline__ float us2f(unsigned short u) {
    union { unsigned int i; float f; } c; c.i = ((unsigned int)u) << 16; return c.f;
}
__device__ __forceinline__ unsigned short f2us(float f) {  // RNE bf16 pack
    union { float f; unsigned u; } c; c.f = f;
    unsigned r = c.u + 0x7FFF + ((c.u >> 16) & 1);
    return (unsigned short)(r >> 16);
}
// flag-aware scalar load (bf=1 -> bf16, bf=0 -> fp32), index in elements
__device__ __forceinline__ float ldw(const void* p, long i, int bf) {
    return bf ? us2f(((const unsigned short*)p)[i]) : ((const float*)p)[i];
}
__device__ __forceinline__ float lrelu(float x) { return x > 0.f ? x : NEG_SLOPE * x; }
__device__ __forceinline__ float wsum(float x) {
#pragma unroll
    for (int o = 32; o > 0; o >>= 1) x += __shfl_xor(x, o);
    return x;
}
__device__ __forceinline__ float wmaxr(float x) {
#pragma unroll
    for (int o = 32; o > 0; o >>= 1) x = fmaxf(x, __shfl_xor(x, o));
    return x;
}
__device__ __forceinline__ float pick4(float4 v, int h) {
    return h == 0 ? v.x : (h == 1 ? v.y : (h == 2 ? v.z : v.w));
}

// ---------- dtype sniff: fp32 data -> |v|<1e6 ; bf16-pairs read as fp32 -> |v|>=2^113 or NaN ----------
__global__ void detect_kernel(const float* __restrict__ x, int* __restrict__ flag) {
    float v = x[threadIdx.x];
    int bad = (!(v == v)) || (fabsf(v) > 1e6f);
    unsigned long long m = __ballot(bad);
    if (threadIdx.x == 0) flag[0] = (m != 0ull) ? 1 : 0;
}

// ---------- CSR build ----------
__global__ __launch_bounds__(256) void zero_int_kernel(int* p, int n) {
    int i = blockIdx.x * 256 + threadIdx.x;
    if (i < n) p[i] = 0;
}
__global__ __launch_bounds__(256) void zero_float_kernel(float* p, int n) {
    int i = blockIdx.x * 256 + threadIdx.x;
    if (i < n) p[i] = 0.f;
}
__global__ __launch_bounds__(256) void count_kernel(const int* __restrict__ dst, int E, int* __restrict__ deg) {
    int e = blockIdx.x * 256 + threadIdx.x;
    if (e < E) atomicAdd(&deg[dst[e]], 1);
}
__global__ __launch_bounds__(256) void scan_kernel(const int* __restrict__ deg, int* __restrict__ row_ptr, int N) {
    __shared__ int part[256];
    int t = threadIdx.x;
    int per = (N + 255) / 256;
    int lo = t * per; if (lo > N) lo = N;
    int hi = lo + per; if (hi > N) hi = N;
    int s = 0;
    for (int i = lo; i < hi; ++i) s += deg[i];
    part[t] = s;
    __syncthreads();
    if (t == 0) {
        int run = 0;
        for (int i = 0; i < 256; ++i) { int v = part[i]; part[i] = run; run += v; }
    }
    __syncthreads();
    int run = part[t];
    for (int i = lo; i < hi; ++i) { row_ptr[i] = run; run += deg[i]; }
    if (t == 255) row_ptr[N] = run;
}
__global__ __launch_bounds__(256) void copy_int_kernel(const int* __restrict__ a, int* __restrict__ b, int n) {
    int i = blockIdx.x * 256 + threadIdx.x;
    if (i < n) b[i] = a[i];
}
__global__ __launch_bounds__(256) void scatter_kernel(const int* __restrict__ src, const int* __restrict__ dst,
                                                      int E, int* __restrict__ cursor, int* __restrict__ csr) {
    int e = blockIdx.x * 256 + threadIdx.x;
    if (e < E) {
        int p = atomicAdd(&cursor[dst[e]], 1);
        csr[p] = src[e];
    }
}

// ---------- tiled GEMM: C[M,128] = act(A[M,K] @ B[K,128] + bias) ----------
// a_input=1: A is a harness input (dtype per flag). a_input=0: A is our fp32 buffer.
// B/bias are harness inputs (dtype per flag). C_BF: 1 -> bf16 out, 0 -> fp32 out.
template <int C_BF>
__global__ __launch_bounds__(256) void gemm_kernel(const void* __restrict__ Ap, int a_input,
                                                   const void* __restrict__ Bp, long b_off,
                                                   const void* __restrict__ bias, long bias_off,
                                                   void* __restrict__ Cp,
                                                   int M, int K, int do_relu, const int* __restrict__ flagp) {
    __shared__ float As[64][33];
    __shared__ float Bs[32][132];
    const int bf = flagp[0];
    const int a_bf = a_input ? bf : 0;
    const int t = threadIdx.x;
    const int tx = t & 15, ty = t >> 4;
    const int block_row = blockIdx.x * 64;
    const int ar = t >> 2, ac = (t & 3) * 8;   // A tile: 64 x 32, 8 elems/thread
    const int br = t >> 3, bc = (t & 7) * 16;  // B tile: 32 x 128, 16 elems/thread

    float acc[4][8];
#pragma unroll
    for (int i = 0; i < 4; ++i)
#pragma unroll
        for (int j = 0; j < 8; ++j) acc[i][j] = 0.f;

    for (int k0 = 0; k0 < K; k0 += 32) {
        const int grow = block_row + ar;
        if (grow < M) {
            const long aidx = (long)grow * K + k0 + ac;
            if (a_bf) {
                const unsigned short* ap = (const unsigned short*)Ap + aidx;
                ushort4 u0 = *(const ushort4*)ap;
                ushort4 u1 = *(const ushort4*)(ap + 4);
                As[ar][ac + 0] = us2f(u0.x); As[ar][ac + 1] = us2f(u0.y);
                As[ar][ac + 2] = us2f(u0.z); As[ar][ac + 3] = us2f(u0.w);
                As[ar][ac + 4] = us2f(u1.x); As[ar][ac + 5] = us2f(u1.y);
                As[ar][ac + 6] = us2f(u1.z); As[ar][ac + 7] = us2f(u1.w);
            } else {
                const float* ap = (const float*)Ap + aidx;
                float4 f0 = *(const float4*)ap;
                float4 f1 = *(const float4*)(ap + 4);
                As[ar][ac + 0] = f0.x; As[ar][ac + 1] = f0.y; As[ar][ac + 2] = f0.z; As[ar][ac + 3] = f0.w;
                As[ar][ac + 4] = f1.x; As[ar][ac + 5] = f1.y; As[ar][ac + 6] = f1.z; As[ar][ac + 7] = f1.w;
            }
        } else {
#pragma unroll
            for (int u = 0; u < 8; ++u) As[ar][ac + u] = 0.f;
        }
        {
            const long bidx = b_off + (long)(k0 + br) * HID + bc;
            if (bf) {
                const unsigned short* bp = (const unsigned short*)Bp + bidx;
#pragma unroll
                for (int q = 0; q < 4; ++q) {
                    ushort4 v = *(const ushort4*)(bp + q * 4);
                    Bs[br][bc + q * 4 + 0] = us2f(v.x);
                    Bs[br][bc + q * 4 + 1] = us2f(v.y);
                    Bs[br][bc + q * 4 + 2] = us2f(v.z);
                    Bs[br][bc + q * 4 + 3] = us2f(v.w);
                }
            } else {
                const float* bp = (const float*)Bp + bidx;
#pragma unroll
                for (int q = 0; q < 4; ++q) {
                    float4 v = *(const float4*)(bp + q * 4);
                    Bs[br][bc + q * 4 + 0] = v.x;
                    Bs[br][bc + q * 4 + 1] = v.y;
                    Bs[br][bc + q * 4 + 2] = v.z;
                    Bs[br][bc + q * 4 + 3] = v.w;
                }
            }
        }
        __syncthreads();
#pragma unroll
        for (int kk = 0; kk < 32; ++kk) {
            float4 b0 = *(const float4*)&Bs[kk][tx * 8];
            float4 b1 = *(const float4*)&Bs[kk][tx * 8 + 4];
            float bv[8] = {b0.x, b0.y, b0.z, b0.w, b1.x, b1.y, b1.z, b1.w};
#pragma unroll
            for (int i = 0; i < 4; ++i) {
                float a = As[ty * 4 + i][kk];
#pragma unroll
                for (int j = 0; j < 8; ++j) acc[i][j] = fmaf(a, bv[j], acc[i][j]);
            }
        }
        __syncthreads();
    }

    float bb[8];
#pragma unroll
    for (int j = 0; j < 8; ++j) bb[j] = bias ? ldw(bias, bias_off + tx * 8 + j, bf) : 0.f;

#pragma unroll
    for (int i = 0; i < 4; ++i) {
        const int r = block_row + ty * 4 + i;
        if (r < M) {
            float o[8];
#pragma unroll
            for (int j = 0; j < 8; ++j) {
                o[j] = acc[i][j] + bb[j];
                if (do_relu) o[j] = fmaxf(o[j], 0.f);
            }
            if (C_BF) {
                unsigned short* cp = (unsigned short*)Cp + (long)r * HID + tx * 8;
                *(ushort4*)cp = make_ushort4(f2us(o[0]), f2us(o[1]), f2us(o[2]), f2us(o[3]));
                *(ushort4*)(cp + 4) = make_ushort4(f2us(o[4]), f2us(o[5]), f2us(o[6]), f2us(o[7]));
            } else {
                float* cp = (float*)Cp + (long)r * HID + tx * 8;
                *(float4*)cp = make_float4(o[0], o[1], o[2], o[3]);
                *(float4*)(cp + 4) = make_float4(o[4], o[5], o[6], o[7]);
            }
        }
    }
}

// ---------- per-node attention scalars: asrc/adst [N,4] (hp is bf16) ----------
__global__ __launch_bounds__(256) void attn_kernel(const unsigned short* __restrict__ hp,
                                                   const void* __restrict__ att_src,
                                                   const void* __restrict__ att_dst, long a_off,
                                                   float* __restrict__ asrc, float* __restrict__ adst,
                                                   int N, const int* __restrict__ flagp) {
    __shared__ float sA[128], sD[128];
    const int bf = flagp[0];
    const int t = threadIdx.x;
    if (t < 128) { sA[t] = ldw(att_src, a_off + t, bf); sD[t] = ldw(att_dst, a_off + t, bf); }
    __syncthreads();
    const int gid = blockIdx.x * 256 + t;
    if (gid >= N * 4) return;
    const int n = gid >> 2, hd = gid & 3;
    const unsigned short* p = hp + (size_t)n * HID + hd * 32;
    float s1 = 0.f, s2 = 0.f;
#pragma unroll
    for (int q = 0; q < 4; ++q) {
        uint4 v = ((const uint4*)p)[q];  // 8 bf16
        unsigned arr[4] = {v.x, v.y, v.z, v.w};
#pragma unroll
        for (int j = 0; j < 4; ++j) {
            const int k = q * 8 + j * 2;
            float lo = us2f((unsigned short)(arr[j] & 0xffffu));
            float hi = us2f((unsigned short)(arr[j] >> 16));
            s1 += lo * sA[hd * 32 + k] + hi * sA[hd * 32 + k + 1];
            s2 += lo * sD[hd * 32 + k] + hi * sD[hd * 32 + k + 1];
        }
    }
    asrc[gid] = s1;
    adst[gid] = s2;
}

// ---------- GAT aggregate + bias + LN + ReLU + residual (one wave per dst node, shuffle-only) ----------
__global__ __launch_bounds__(256) void gat_kernel(float* __restrict__ h,                  // [N,128] fp32 residual in/out
                                                  const unsigned short* __restrict__ hp,  // [N,128] bf16 projected
                                                  const float* __restrict__ asrc,
                                                  const float* __restrict__ adst,
                                                  const int* __restrict__ row_ptr,
                                                  const int* __restrict__ csr,
                                                  const void* __restrict__ bgat,
                                                  const void* __restrict__ lng,
                                                  const void* __restrict__ lnb, long w_off,
                                                  int N, const int* __restrict__ flagp) {
    const int bf = flagp[0];
    const int lane = threadIdx.x & 63;
    const int head = lane >> 4;
    const int n = (blockIdx.x << 2) | (threadIdx.x >> 6);
    if (n >= N) return;

    const int e0 = row_ptr[n], e1 = row_ptr[n + 1];
    const float4 ad4 = *(const float4*)(adst + (size_t)n * 4);
    const float4 as4 = *(const float4*)(asrc + (size_t)n * 4);
    float4 es;  // self-loop logits
    es.x = lrelu(as4.x + ad4.x); es.y = lrelu(as4.y + ad4.y);
    es.z = lrelu(as4.z + ad4.z); es.w = lrelu(as4.w + ad4.w);

    // phase A: per-head max over in-edges (seeded with self-loop)
    float4 m = es;
    for (int e = e0 + lane; e < e1; e += 64) {
        const int s = csr[e];
        const float4 a = *(const float4*)(asrc + (size_t)s * 4);
        m.x = fmaxf(m.x, lrelu(a.x + ad4.x));
        m.y = fmaxf(m.y, lrelu(a.y + ad4.y));
        m.z = fmaxf(m.z, lrelu(a.z + ad4.z));
        m.w = fmaxf(m.w, lrelu(a.w + ad4.w));
    }
    m.x = wmaxr(m.x); m.y = wmaxr(m.y); m.z = wmaxr(m.z); m.w = wmaxr(m.w);

    float4 exs;
    exs.x = expf(es.x - m.x); exs.y = expf(es.y - m.y);
    exs.z = expf(es.z - m.z); exs.w = expf(es.w - m.w);

    // phase B: accumulate exp-weighted features + denominator (normalize at end)
    const float wself = pick4(exs, head);
    const unsigned hv0 = *(const unsigned*)(hp + (size_t)n * HID + lane * 2);
    float2 acc;
    acc.x = wself * us2f((unsigned short)(hv0 & 0xffffu));
    acc.y = wself * us2f((unsigned short)(hv0 >> 16));
    float4 dn = make_float4(0.f, 0.f, 0.f, 0.f);

    for (int base = e0; base < e1; base += 64) {
        const int cnt = min(64, e1 - base);
        int s = 0;
        float4 ex4 = make_float4(0.f, 0.f, 0.f, 0.f);
        if (base + lane < e1) {
            s = csr[base + lane];
            const float4 a = *(const float4*)(asrc + (size_t)s * 4);
            ex4.x = expf(lrelu(a.x + ad4.x) - m.x);
            ex4.y = expf(lrelu(a.y + ad4.y) - m.y);
            ex4.z = expf(lrelu(a.z + ad4.z) - m.z);
            ex4.w = expf(lrelu(a.w + ad4.w) - m.w);
            dn.x += ex4.x; dn.y += ex4.y; dn.z += ex4.z; dn.w += ex4.w;
        }
        // broadcast each staged edge via shuffles (no LDS, no barrier semantics needed)
        for (int i = 0; i < cnt; ++i) {
            const int ss = __shfl(s, i);
            const float wx = __shfl(ex4.x, i);
            const float wy = __shfl(ex4.y, i);
            const float wz = __shfl(ex4.z, i);
            const float ww = __shfl(ex4.w, i);
            const float wgt = head == 0 ? wx : (head == 1 ? wy : (head == 2 ? wz : ww));
            const unsigned uv = *(const unsigned*)(hp + (size_t)ss * HID + lane * 2);
            acc.x = fmaf(wgt, us2f((unsigned short)(uv & 0xffffu)), acc.x);
            acc.y = fmaf(wgt, us2f((unsigned short)(uv >> 16)), acc.y);
        }
    }
    dn.x = wsum(dn.x); dn.y = wsum(dn.y); dn.z = wsum(dn.z); dn.w = wsum(dn.w);
    dn.x += exs.x; dn.y += exs.y; dn.z += exs.z; dn.w += exs.w;

    const float invd = 1.f / fmaxf(pick4(dn, head), 1e-16f);
    acc.x *= invd; acc.y *= invd;
    acc.x += ldw(bgat, w_off + lane * 2, bf);
    acc.y += ldw(bgat, w_off + lane * 2 + 1, bf);

    // LayerNorm over 128
    float mean = wsum(acc.x + acc.y) * (1.f / 128.f);
    float dx = acc.x - mean, dy = acc.y - mean;
    float var = wsum(dx * dx + dy * dy) * (1.f / 128.f);
    float rstd = rsqrtf(var + LN_EPS);
    float o0 = dx * rstd * ldw(lng, w_off + lane * 2, bf)     + ldw(lnb, w_off + lane * 2, bf);
    float o1 = dy * rstd * ldw(lng, w_off + lane * 2 + 1, bf) + ldw(lnb, w_off + lane * 2 + 1, bf);
    o0 = fmaxf(o0, 0.f);
    o1 = fmaxf(o1, 0.f);

    const float2 r = *(const float2*)(h + (size_t)n * HID + lane * 2);
    *(float2*)(h + (size_t)n * HID + lane * 2) = make_float2(o0 + r.x, o1 + r.y);
}

// ---------- pooling ----------
__global__ __launch_bounds__(256) void pool_accum_kernel(const float* __restrict__ h, const int* __restrict__ batch,
                                                         float* __restrict__ sums, float* __restrict__ cnt, int N) {
    const int i = blockIdx.x * 256 + threadIdx.x;
    if (i >= N * 32) return;
    const int n = i >> 5, q = i & 31;
    const int g = batch[n];
    const float4 v = *(const float4*)(h + (size_t)n * HID + q * 4);
    atomicAdd(&sums[(size_t)g * HID + q * 4 + 0], v.x);
    atomicAdd(&sums[(size_t)g * HID + q * 4 + 1], v.y);
    atomicAdd(&sums[(size_t)g * HID + q * 4 + 2], v.z);
    atomicAdd(&sums[(size_t)g * HID + q * 4 + 3], v.w);
    if (q == 0) atomicAdd(&cnt[g], 1.0f);
}
__global__ __launch_bounds__(256) void pool_final_kernel(const float* __restrict__ sums, const float* __restrict__ cnt,
                                                         void* __restrict__ out, int total, const int* __restrict__ flagp) {
    const int i = blockIdx.x * 256 + threadIdx.x;
    if (i >= total) return;
    const int g = i >> 7;
    const float v = sums[i] / fmaxf(cnt[g], 1.0f);
    if (flagp[0]) ((unsigned short*)out)[i] = f2us(v);
    else          ((float*)out)[i] = v;
}

// ---------- launch ----------
extern "C" void kernel_launch(void* const* d_in, const int* in_sizes, int n_in,
                              void* d_out, int out_size, void* d_ws, size_t ws_size,
                              hipStream_t stream) {
    const void* x     = d_in[0];
    const void* W_in  = d_in[1];
    const void* b_in  = d_in[2];
    const void* W_gat = d_in[3];
    const void* att_s = d_in[4];
    const void* att_d = d_in[5];
    const void* b_gat = d_in[6];
    const void* ln_g  = d_in[7];
    const void* ln_b  = d_in[8];
    const int* edge_index = (const int*)d_in[9];
    const int* batch      = (const int*)d_in[10];

    const int N = in_sizes[10];
    const int E = in_sizes[9] / 2;
    const int IN_DIM = in_sizes[0] / N;
    const int n_graphs = out_size / HID;

    const int* esrc = edge_index;
    const int* edst = edge_index + E;

    // workspace carve (small/critical arrays first; total ~87.4 MB)
    char* w = (char*)d_ws;
    auto carve = [&](size_t bytes) -> void* {
        void* p = (void*)w;
        w += (bytes + 255) & ~(size_t)255;
        return p;
    };
    int* flag            = (int*)carve(256);
    int* row_ptr         = (int*)carve((size_t)(N + 1) * 4);
    int* cursor          = (int*)carve((size_t)N * 4);
    int* csr             = (int*)carve((size_t)E * 4);
    float* asrc          = (float*)carve((size_t)N * 4 * 4);
    float* adst          = (float*)carve((size_t)N * 4 * 4);
    float* sums          = (float*)carve(((size_t)n_graphs * HID + n_graphs) * 4);
    float* cnt           = sums + (size_t)n_graphs * HID;
    float* h             = (float*)carve((size_t)N * HID * 4);          // fp32 residual stream
    unsigned short* hp   = (unsigned short*)carve((size_t)N * HID * 2); // bf16 projected features
    (void)ws_size; (void)n_in;

    // dtype sniff (must precede all weight-reading kernels)
    detect_kernel<<<1, 64, 0, stream>>>((const float*)x, flag);

    // CSR by destination (deg lives in `cursor` temporarily)
    zero_int_kernel<<<(N + 255) / 256, 256, 0, stream>>>(cursor, N);
    count_kernel<<<(E + 255) / 256, 256, 0, stream>>>(edst, E, cursor);
    scan_kernel<<<1, 256, 0, stream>>>(cursor, row_ptr, N);
    copy_int_kernel<<<(N + 255) / 256, 256, 0, stream>>>(row_ptr, cursor, N);
    scatter_kernel<<<(E + 255) / 256, 256, 0, stream>>>(esrc, edst, E, cursor, csr);

    // input projection: h = relu(x @ W_in + b_in)  (fp32 out)
    gemm_kernel<0><<<(N + 63) / 64, 256, 0, stream>>>(x, 1, W_in, 0, b_in, 0, h, N, IN_DIM, 1, flag);

    for (int l = 0; l < 3; ++l) {
        // hp = h @ W_gat[l]  (bf16 out)
        gemm_kernel<1><<<(N + 63) / 64, 256, 0, stream>>>(h, 0, W_gat, (long)l * HID * HID,
                                                          nullptr, 0, hp, N, HID, 0, flag);
        attn_kernel<<<(N * 4 + 255) / 256, 256, 0, stream>>>(hp, att_s, att_d, (long)l * HID,
                                                             asrc, adst, N, flag);
        gat_kernel<<<(N + 3) / 4, 256, 0, stream>>>(h, hp, asrc, adst, row_ptr, csr,
                                                    b_gat, ln_g, ln_b, (long)l * HID, N, flag);
    }

    zero_float_kernel<<<(n_graphs * HID + n_graphs + 255) / 256, 256, 0, stream>>>(sums, n_graphs * HID + n_graphs);
    pool_accum_kernel<<<(N * 32 + 255) / 256, 256, 0, stream>>>(h, batch, sums, cnt, N);
    pool_final_kernel<<<(n_graphs * HID + 255) / 256, 256, 0, stream>>>(sums, cnt, d_out, n_graphs * HID, flag);
}

// Round 3
// 1322.308 us; speedup vs baseline: 1.4478x; 1.4478x over previous
//
#include <hip/hip_runtime.h>
#include <hip/hip_bf16.h>

#define HID 128
#define NEG_SLOPE 0.2f
#define LN_EPS 1e-5f

typedef __attribute__((ext_vector_type(8))) short short8;
typedef __attribute__((ext_vector_type(4))) float floatx4;

// ---------- helpers ----------
__device__ __forceinline__ float us2f(unsigned short u) {
    union { unsigned int i; float f; } c; c.i = ((unsigned int)u) << 16; return c.f;
}
__device__ __forceinline__ unsigned short f2us(float f) {  // RNE bf16 pack
    union { float f; unsigned u; } c; c.f = f;
    unsigned r = c.u + 0x7FFF + ((c.u >> 16) & 1);
    return (unsigned short)(r >> 16);
}
__device__ __forceinline__ unsigned pack2(float a, float b) {
    return (unsigned)f2us(a) | ((unsigned)f2us(b) << 16);
}
__device__ __forceinline__ float ldw(const void* p, long i, int bf) {
    return bf ? us2f(((const unsigned short*)p)[i]) : ((const float*)p)[i];
}
__device__ __forceinline__ float lrelu(float x) { return x > 0.f ? x : NEG_SLOPE * x; }
__device__ __forceinline__ float wsum(float x) {
#pragma unroll
    for (int o = 32; o > 0; o >>= 1) x += __shfl_xor(x, o);
    return x;
}
__device__ __forceinline__ float wmaxr(float x) {
#pragma unroll
    for (int o = 32; o > 0; o >>= 1) x = fmaxf(x, __shfl_xor(x, o));
    return x;
}
__device__ __forceinline__ float pick4(float4 v, int h) {
    return h == 0 ? v.x : (h == 1 ? v.y : (h == 2 ? v.z : v.w));
}

// ---------- dtype sniff ----------
__global__ void detect_kernel(const float* __restrict__ x, int* __restrict__ flag) {
    float v = x[threadIdx.x];
    int bad = (!(v == v)) || (fabsf(v) > 1e6f);
    unsigned long long m = __ballot(bad);
    if (threadIdx.x == 0) flag[0] = (m != 0ull) ? 1 : 0;
}

// ---------- CSR build ----------
__global__ __launch_bounds__(256) void zero_int_kernel(int* p, int n) {
    int i = blockIdx.x * 256 + threadIdx.x;
    if (i < n) p[i] = 0;
}
__global__ __launch_bounds__(256) void count_kernel(const int* __restrict__ dst, int E, int* __restrict__ deg) {
    int e = blockIdx.x * 256 + threadIdx.x;
    if (e < E) atomicAdd(&deg[dst[e]], 1);
}
__global__ __launch_bounds__(256) void scan_kernel(const int* __restrict__ deg, int* __restrict__ row_ptr, int N) {
    __shared__ int part[256];
    int t = threadIdx.x;
    int per = (N + 255) / 256;
    int lo = t * per; if (lo > N) lo = N;
    int hi = lo + per; if (hi > N) hi = N;
    int s = 0;
    for (int i = lo; i < hi; ++i) s += deg[i];
    part[t] = s;
    __syncthreads();
    if (t == 0) {
        int run = 0;
        for (int i = 0; i < 256; ++i) { int v = part[i]; part[i] = run; run += v; }
    }
    __syncthreads();
    int run = part[t];
    for (int i = lo; i < hi; ++i) { row_ptr[i] = run; run += deg[i]; }
    if (t == 255) row_ptr[N] = run;
}
__global__ __launch_bounds__(256) void copy_int_kernel(const int* __restrict__ a, int* __restrict__ b, int n) {
    int i = blockIdx.x * 256 + threadIdx.x;
    if (i < n) b[i] = a[i];
}
__global__ __launch_bounds__(256) void scatter_kernel(const int* __restrict__ src, const int* __restrict__ dst,
                                                      int E, int* __restrict__ cursor, int* __restrict__ csr) {
    int e = blockIdx.x * 256 + threadIdx.x;
    if (e < E) {
        int p = atomicAdd(&cursor[dst[e]], 1);
        csr[p] = src[e];
    }
}

// ---------- W transpose+convert: Wt[n][k] = bf16(W[w_off + k*128 + n]), n<128, k<K ----------
__global__ __launch_bounds__(256) void transpose_w_kernel(const void* __restrict__ W, long w_off, int K,
                                                          unsigned short* __restrict__ Wt,
                                                          const int* __restrict__ flagp) {
    const int bf = flagp[0];
    const int i = blockIdx.x * 256 + threadIdx.x;
    if (i >= 128 * K) return;
    const int n = i / K, k = i - n * K;
    const long s = w_off + (long)k * 128 + n;
    Wt[i] = bf ? ((const unsigned short*)W)[s] : f2us(((const float*)W)[s]);
}

// ---------- MFMA GEMM: C[M,128] = act(A[M,K] @ B[K,128] + bias) ----------
// A: a_bf_input ? flag-dtype harness input : fp32 workspace buffer.
// Bt: [128][K] bf16 (pre-transposed). C_BF: 1 -> bf16 out, 0 -> fp32 out.
// Tile: 128 rows x 128 cols, BK=32, 256 threads (4 waves, 32 rows/wave).
template <int C_BF>
__global__ __launch_bounds__(256) void mfma_gemm_kernel(const void* __restrict__ Ap, int a_input,
                                                        const unsigned short* __restrict__ Bt,
                                                        const void* __restrict__ bias, long bias_off,
                                                        void* __restrict__ Cp,
                                                        int M, int K, int do_relu,
                                                        const int* __restrict__ flagp) {
    __shared__ unsigned short As[128 * 40];  // row stride 40 bf16 (80 B, breaks bank aliasing)
    __shared__ unsigned short Bs[128 * 40];  // BsT[n][k], same stride
    const int bf = flagp[0];
    const int a_bf = a_input ? bf : 2;  // 2 == fp32 workspace
    const int t = threadIdx.x;
    const int bm = blockIdx.x * 128;
    const int lane = t & 63, wave = t >> 6;
    const int r = lane & 15, quad = lane >> 4;
    const int srow = t >> 1, skh = (t & 1) * 16;  // staging: 16 bf16 per thread per tile

    floatx4 acc[2][8];
#pragma unroll
    for (int mt = 0; mt < 2; ++mt)
#pragma unroll
        for (int nt = 0; nt < 8; ++nt)
#pragma unroll
            for (int q = 0; q < 4; ++q) acc[mt][nt][q] = 0.f;

    for (int k0 = 0; k0 < K; k0 += 32) {
        // stage A (convert to bf16)
        {
            const int grow = bm + srow;
            uint4 u0 = make_uint4(0, 0, 0, 0), u1 = u0;
            if (grow < M) {
                const long aidx = (long)grow * K + k0 + skh;
                if (a_bf == 1) {
                    const unsigned short* ap = (const unsigned short*)Ap + aidx;
                    u0 = ((const uint4*)ap)[0];
                    u1 = ((const uint4*)ap)[1];
                } else {
                    const float* ap = (const float*)Ap + aidx;
                    float4 f0 = ((const float4*)ap)[0];
                    float4 f1 = ((const float4*)ap)[1];
                    float4 f2 = ((const float4*)ap)[2];
                    float4 f3 = ((const float4*)ap)[3];
                    u0 = make_uint4(pack2(f0.x, f0.y), pack2(f0.z, f0.w), pack2(f1.x, f1.y), pack2(f1.z, f1.w));
                    u1 = make_uint4(pack2(f2.x, f2.y), pack2(f2.z, f2.w), pack2(f3.x, f3.y), pack2(f3.z, f3.w));
                }
            }
            *(uint4*)&As[srow * 40 + skh]     = u0;
            *(uint4*)&As[srow * 40 + skh + 8] = u1;
        }
        // stage B (already bf16, [n][k] layout)
        {
            const unsigned short* bp = Bt + (long)srow * K + k0 + skh;
            uint4 v0 = ((const uint4*)bp)[0];
            uint4 v1 = ((const uint4*)bp)[1];
            *(uint4*)&Bs[srow * 40 + skh]     = v0;
            *(uint4*)&Bs[srow * 40 + skh + 8] = v1;
        }
        __syncthreads();

        short8 afr[2];
        afr[0] = *(const short8*)&As[(wave * 32 + r) * 40 + quad * 8];
        afr[1] = *(const short8*)&As[(wave * 32 + 16 + r) * 40 + quad * 8];
#pragma unroll
        for (int nt = 0; nt < 8; ++nt) {
            short8 bfr = *(const short8*)&Bs[(nt * 16 + r) * 40 + quad * 8];
            acc[0][nt] = __builtin_amdgcn_mfma_f32_16x16x32_bf16(afr[0], bfr, acc[0][nt], 0, 0, 0);
            acc[1][nt] = __builtin_amdgcn_mfma_f32_16x16x32_bf16(afr[1], bfr, acc[1][nt], 0, 0, 0);
        }
        __syncthreads();
    }

    float bb[8];
#pragma unroll
    for (int nt = 0; nt < 8; ++nt) bb[nt] = bias ? ldw(bias, bias_off + nt * 16 + r, bf) : 0.f;

#pragma unroll
    for (int mt = 0; mt < 2; ++mt) {
        const int gr0 = bm + wave * 32 + mt * 16 + quad * 4;
#pragma unroll
        for (int reg = 0; reg < 4; ++reg) {
            const int grow = gr0 + reg;
            if (grow < M) {
#pragma unroll
                for (int nt = 0; nt < 8; ++nt) {
                    float v = acc[mt][nt][reg] + bb[nt];
                    if (do_relu) v = fmaxf(v, 0.f);
                    const long ci = (long)grow * HID + nt * 16 + r;
                    if (C_BF) ((unsigned short*)Cp)[ci] = f2us(v);
                    else      ((float*)Cp)[ci] = v;
                }
            }
        }
    }
}

// ---------- per-node attention scalars: asrc/adst [N,4] (hp is bf16) ----------
__global__ __launch_bounds__(256) void attn_kernel(const unsigned short* __restrict__ hp,
                                                   const void* __restrict__ att_src,
                                                   const void* __restrict__ att_dst, long a_off,
                                                   float* __restrict__ asrc, float* __restrict__ adst,
                                                   int N, const int* __restrict__ flagp) {
    __shared__ float sA[128], sD[128];
    const int bf = flagp[0];
    const int t = threadIdx.x;
    if (t < 128) { sA[t] = ldw(att_src, a_off + t, bf); sD[t] = ldw(att_dst, a_off + t, bf); }
    __syncthreads();
    const int gid = blockIdx.x * 256 + t;
    if (gid >= N * 4) return;
    const int n = gid >> 2, hd = gid & 3;
    const unsigned short* p = hp + (size_t)n * HID + hd * 32;
    float s1 = 0.f, s2 = 0.f;
#pragma unroll
    for (int q = 0; q < 4; ++q) {
        uint4 v = ((const uint4*)p)[q];  // 8 bf16
        unsigned arr[4] = {v.x, v.y, v.z, v.w};
#pragma unroll
        for (int j = 0; j < 4; ++j) {
            const int k = q * 8 + j * 2;
            float lo = us2f((unsigned short)(arr[j] & 0xffffu));
            float hi = us2f((unsigned short)(arr[j] >> 16));
            s1 += lo * sA[hd * 32 + k] + hi * sA[hd * 32 + k + 1];
            s2 += lo * sD[hd * 32 + k] + hi * sD[hd * 32 + k + 1];
        }
    }
    asrc[gid] = s1;
    adst[gid] = s2;
}

// ---------- GAT aggregate + bias + LN + ReLU + residual (one wave per dst node) ----------
__global__ __launch_bounds__(256) void gat_kernel(float* __restrict__ h,
                                                  const unsigned short* __restrict__ hp,
                                                  const float* __restrict__ asrc,
                                                  const float* __restrict__ adst,
                                                  const int* __restrict__ row_ptr,
                                                  const int* __restrict__ csr,
                                                  const void* __restrict__ bgat,
                                                  const void* __restrict__ lng,
                                                  const void* __restrict__ lnb, long w_off,
                                                  int N, const int* __restrict__ flagp) {
    const int bf = flagp[0];
    const int lane = threadIdx.x & 63;
    const int head = lane >> 4;
    const int n = (blockIdx.x << 2) | (threadIdx.x >> 6);
    if (n >= N) return;

    const int e0 = row_ptr[n], e1 = row_ptr[n + 1];
    const float4 ad4 = *(const float4*)(adst + (size_t)n * 4);
    const float4 as4 = *(const float4*)(asrc + (size_t)n * 4);
    float4 es;
    es.x = lrelu(as4.x + ad4.x); es.y = lrelu(as4.y + ad4.y);
    es.z = lrelu(as4.z + ad4.z); es.w = lrelu(as4.w + ad4.w);

    float4 m = es;
    for (int e = e0 + lane; e < e1; e += 64) {
        const int s = csr[e];
        const float4 a = *(const float4*)(asrc + (size_t)s * 4);
        m.x = fmaxf(m.x, lrelu(a.x + ad4.x));
        m.y = fmaxf(m.y, lrelu(a.y + ad4.y));
        m.z = fmaxf(m.z, lrelu(a.z + ad4.z));
        m.w = fmaxf(m.w, lrelu(a.w + ad4.w));
    }
    m.x = wmaxr(m.x); m.y = wmaxr(m.y); m.z = wmaxr(m.z); m.w = wmaxr(m.w);

    float4 exs;
    exs.x = expf(es.x - m.x); exs.y = expf(es.y - m.y);
    exs.z = expf(es.z - m.z); exs.w = expf(es.w - m.w);

    const float wself = pick4(exs, head);
    const unsigned hv0 = *(const unsigned*)(hp + (size_t)n * HID + lane * 2);
    float2 acc;
    acc.x = wself * us2f((unsigned short)(hv0 & 0xffffu));
    acc.y = wself * us2f((unsigned short)(hv0 >> 16));
    float4 dn = make_float4(0.f, 0.f, 0.f, 0.f);

    for (int base = e0; base < e1; base += 64) {
        const int cnt = min(64, e1 - base);
        int s = 0;
        float4 ex4 = make_float4(0.f, 0.f, 0.f, 0.f);
        if (base + lane < e1) {
            s = csr[base + lane];
            const float4 a = *(const float4*)(asrc + (size_t)s * 4);
            ex4.x = expf(lrelu(a.x + ad4.x) - m.x);
            ex4.y = expf(lrelu(a.y + ad4.y) - m.y);
            ex4.z = expf(lrelu(a.z + ad4.z) - m.z);
            ex4.w = expf(lrelu(a.w + ad4.w) - m.w);
            dn.x += ex4.x; dn.y += ex4.y; dn.z += ex4.z; dn.w += ex4.w;
        }
        for (int i = 0; i < cnt; ++i) {
            const int ss = __shfl(s, i);
            const float wx = __shfl(ex4.x, i);
            const float wy = __shfl(ex4.y, i);
            const float wz = __shfl(ex4.z, i);
            const float ww = __shfl(ex4.w, i);
            const float wgt = head == 0 ? wx : (head == 1 ? wy : (head == 2 ? wz : ww));
            const unsigned uv = *(const unsigned*)(hp + (size_t)ss * HID + lane * 2);
            acc.x = fmaf(wgt, us2f((unsigned short)(uv & 0xffffu)), acc.x);
            acc.y = fmaf(wgt, us2f((unsigned short)(uv >> 16)), acc.y);
        }
    }
    dn.x = wsum(dn.x); dn.y = wsum(dn.y); dn.z = wsum(dn.z); dn.w = wsum(dn.w);
    dn.x += exs.x; dn.y += exs.y; dn.z += exs.z; dn.w += exs.w;

    const float invd = 1.f / fmaxf(pick4(dn, head), 1e-16f);
    acc.x *= invd; acc.y *= invd;
    acc.x += ldw(bgat, w_off + lane * 2, bf);
    acc.y += ldw(bgat, w_off + lane * 2 + 1, bf);

    float mean = wsum(acc.x + acc.y) * (1.f / 128.f);
    float dx = acc.x - mean, dy = acc.y - mean;
    float var = wsum(dx * dx + dy * dy) * (1.f / 128.f);
    float rstd = rsqrtf(var + LN_EPS);
    float o0 = dx * rstd * ldw(lng, w_off + lane * 2, bf)     + ldw(lnb, w_off + lane * 2, bf);
    float o1 = dy * rstd * ldw(lng, w_off + lane * 2 + 1, bf) + ldw(lnb, w_off + lane * 2 + 1, bf);
    o0 = fmaxf(o0, 0.f);
    o1 = fmaxf(o1, 0.f);

    const float2 r = *(const float2*)(h + (size_t)n * HID + lane * 2);
    *(float2*)(h + (size_t)n * HID + lane * 2) = make_float2(o0 + r.x, o1 + r.y);
}

// ---------- pooling (batch is sorted -> per-graph contiguous ranges, no atomics) ----------
__global__ __launch_bounds__(256) void pool_kernel(const float* __restrict__ h, const int* __restrict__ batch,
                                                   void* __restrict__ out, int N,
                                                   const int* __restrict__ flagp) {
    const int g = blockIdx.x;
    // lower/upper bound of graph g in sorted batch[]
    int a = 0, b = N;
    while (a < b) { int mid = (a + b) >> 1; if (batch[mid] < g) a = mid + 1; else b = mid; }
    const int lo = a;
    b = N;
    while (a < b) { int mid = (a + b) >> 1; if (batch[mid] <= g) a = mid + 1; else b = mid; }
    const int hi = a;

    const int col = threadIdx.x & 127;
    const int half = threadIdx.x >> 7;
    float s = 0.f;
    for (int r = lo + half; r < hi; r += 2) s += h[(size_t)r * HID + col];
    __shared__ float part[128];
    if (half == 0) part[col] = s;
    __syncthreads();
    if (half == 1) {
        const float tot = part[col] + s;
        const float v = tot / fmaxf((float)(hi - lo), 1.f);
        if (flagp[0]) ((unsigned short*)out)[g * HID + col] = f2us(v);
        else          ((float*)out)[g * HID + col] = v;
    }
}

// ---------- launch ----------
extern "C" void kernel_launch(void* const* d_in, const int* in_sizes, int n_in,
                              void* d_out, int out_size, void* d_ws, size_t ws_size,
                              hipStream_t stream) {
    const void* x     = d_in[0];
    const void* W_in  = d_in[1];
    const void* b_in  = d_in[2];
    const void* W_gat = d_in[3];
    const void* att_s = d_in[4];
    const void* att_d = d_in[5];
    const void* b_gat = d_in[6];
    const void* ln_g  = d_in[7];
    const void* ln_b  = d_in[8];
    const int* edge_index = (const int*)d_in[9];
    const int* batch      = (const int*)d_in[10];

    const int N = in_sizes[10];
    const int E = in_sizes[9] / 2;
    const int IN_DIM = in_sizes[0] / N;
    const int n_graphs = out_size / HID;

    const int* esrc = edge_index;
    const int* edst = edge_index + E;

    char* w = (char*)d_ws;
    auto carve = [&](size_t bytes) -> void* {
        void* p = (void*)w;
        w += (bytes + 255) & ~(size_t)255;
        return p;
    };
    int* flag            = (int*)carve(256);
    int* row_ptr         = (int*)carve((size_t)(N + 1) * 4);
    int* cursor          = (int*)carve((size_t)N * 4);
    int* csr             = (int*)carve((size_t)E * 4);
    float* asrc          = (float*)carve((size_t)N * 4 * 4);
    float* adst          = (float*)carve((size_t)N * 4 * 4);
    unsigned short* Wt_in = (unsigned short*)carve((size_t)HID * IN_DIM * 2);
    unsigned short* Wt_g  = (unsigned short*)carve((size_t)HID * HID * 2);
    float* h             = (float*)carve((size_t)N * HID * 4);
    unsigned short* hp   = (unsigned short*)carve((size_t)N * HID * 2);
    (void)ws_size; (void)n_in;

    detect_kernel<<<1, 64, 0, stream>>>((const float*)x, flag);

    // CSR by destination
    zero_int_kernel<<<(N + 255) / 256, 256, 0, stream>>>(cursor, N);
    count_kernel<<<(E + 255) / 256, 256, 0, stream>>>(edst, E, cursor);
    scan_kernel<<<1, 256, 0, stream>>>(cursor, row_ptr, N);
    copy_int_kernel<<<(N + 255) / 256, 256, 0, stream>>>(row_ptr, cursor, N);
    scatter_kernel<<<(E + 255) / 256, 256, 0, stream>>>(esrc, edst, E, cursor, csr);

    // input projection: h = relu(x @ W_in + b_in)
    transpose_w_kernel<<<(HID * IN_DIM + 255) / 256, 256, 0, stream>>>(W_in, 0, IN_DIM, Wt_in, flag);
    mfma_gemm_kernel<0><<<(N + 127) / 128, 256, 0, stream>>>(x, 1, Wt_in, b_in, 0, h, N, IN_DIM, 1, flag);

    for (int l = 0; l < 3; ++l) {
        transpose_w_kernel<<<(HID * HID + 255) / 256, 256, 0, stream>>>(W_gat, (long)l * HID * HID, HID, Wt_g, flag);
        mfma_gemm_kernel<1><<<(N + 127) / 128, 256, 0, stream>>>(h, 0, Wt_g, nullptr, 0, hp, N, HID, 0, flag);
        attn_kernel<<<(N * 4 + 255) / 256, 256, 0, stream>>>(hp, att_s, att_d, (long)l * HID,
                                                             asrc, adst, N, flag);
        gat_kernel<<<(N + 3) / 4, 256, 0, stream>>>(h, hp, asrc, adst, row_ptr, csr,
                                                    b_gat, ln_g, ln_b, (long)l * HID, N, flag);
    }

    pool_kernel<<<n_graphs, 256, 0, stream>>>(h, batch, d_out, N, flag);
}

// Round 4
// 1130.818 us; speedup vs baseline: 1.6929x; 1.1693x over previous
//
#include <hip/hip_runtime.h>
#include <hip/hip_bf16.h>

#define HID 128
#define NEG_SLOPE 0.2f
#define LN_EPS 1e-5f

typedef __attribute__((ext_vector_type(8))) short short8;
typedef __attribute__((ext_vector_type(4))) float floatx4;

// ---------- helpers ----------
__device__ __forceinline__ float us2f(unsigned short u) {
    union { unsigned int i; float f; } c; c.i = ((unsigned int)u) << 16; return c.f;
}
__device__ __forceinline__ float lo2f(unsigned u) {  // low bf16 of packed pair -> float
    union { unsigned int i; float f; } c; c.i = u << 16; return c.f;
}
__device__ __forceinline__ float hi2f(unsigned u) {  // high bf16 of packed pair -> float
    union { unsigned int i; float f; } c; c.i = u & 0xffff0000u; return c.f;
}
__device__ __forceinline__ unsigned short f2us(float f) {  // RNE bf16 pack
    union { float f; unsigned u; } c; c.f = f;
    unsigned r = c.u + 0x7FFF + ((c.u >> 16) & 1);
    return (unsigned short)(r >> 16);
}
__device__ __forceinline__ unsigned pack2(float a, float b) {
    return (unsigned)f2us(a) | ((unsigned)f2us(b) << 16);
}
__device__ __forceinline__ float ldw(const void* p, long i, int bf) {
    return bf ? us2f(((const unsigned short*)p)[i]) : ((const float*)p)[i];
}
__device__ __forceinline__ float lrelu(float x) { return x > 0.f ? x : NEG_SLOPE * x; }
__device__ __forceinline__ float wsum(float x) {
#pragma unroll
    for (int o = 32; o > 0; o >>= 1) x += __shfl_xor(x, o);
    return x;
}
__device__ __forceinline__ float wmaxr(float x) {
#pragma unroll
    for (int o = 32; o > 0; o >>= 1) x = fmaxf(x, __shfl_xor(x, o));
    return x;
}
__device__ __forceinline__ float pick4(float4 v, int h) {
    return h == 0 ? v.x : (h == 1 ? v.y : (h == 2 ? v.z : v.w));
}

// ---------- dtype sniff ----------
__global__ void detect_kernel(const float* __restrict__ x, int* __restrict__ flag) {
    float v = x[threadIdx.x];
    int bad = (!(v == v)) || (fabsf(v) > 1e6f);
    unsigned long long m = __ballot(bad);
    if (threadIdx.x == 0) flag[0] = (m != 0ull) ? 1 : 0;
}

// ---------- CSR build ----------
__global__ __launch_bounds__(256) void zero_int_kernel(int* p, int n) {
    int i = blockIdx.x * 256 + threadIdx.x;
    if (i < n) p[i] = 0;
}
__global__ __launch_bounds__(256) void count_kernel(const int* __restrict__ dst, int E, int* __restrict__ deg) {
    int e = blockIdx.x * 256 + threadIdx.x;
    if (e < E) atomicAdd(&deg[dst[e]], 1);
}
__global__ __launch_bounds__(1024) void scan_kernel(const int* __restrict__ deg, int* __restrict__ row_ptr, int N) {
    __shared__ int part[1024];
    int t = threadIdx.x;
    int per = (N + 1023) / 1024;
    int lo = t * per; if (lo > N) lo = N;
    int hi = lo + per; if (hi > N) hi = N;
    int s = 0;
    for (int i = lo; i < hi; ++i) s += deg[i];
    part[t] = s;
    __syncthreads();
    if (t == 0) {
        int run = 0;
        for (int i = 0; i < 1024; ++i) { int v = part[i]; part[i] = run; run += v; }
    }
    __syncthreads();
    int run = part[t];
    for (int i = lo; i < hi; ++i) { row_ptr[i] = run; run += deg[i]; }
    if (t == 1023) row_ptr[N] = run;
}
__global__ __launch_bounds__(256) void copy_int_kernel(const int* __restrict__ a, int* __restrict__ b, int n) {
    int i = blockIdx.x * 256 + threadIdx.x;
    if (i < n) b[i] = a[i];
}
__global__ __launch_bounds__(256) void scatter_kernel(const int* __restrict__ src, const int* __restrict__ dst,
                                                      int E, int* __restrict__ cursor, int* __restrict__ csr) {
    int e = blockIdx.x * 256 + threadIdx.x;
    if (e < E) {
        int p = atomicAdd(&cursor[dst[e]], 1);
        csr[p] = src[e];
    }
}

// ---------- W transpose+convert: Wt[n][k] = bf16(W[w_off + k*128 + n]) ----------
__global__ __launch_bounds__(256) void transpose_w_kernel(const void* __restrict__ W, long w_off, int K,
                                                          unsigned short* __restrict__ Wt,
                                                          const int* __restrict__ flagp) {
    const int bf = flagp[0];
    const int i = blockIdx.x * 256 + threadIdx.x;
    if (i >= 128 * K) return;
    const int n = i / K, k = i - n * K;
    const long s = w_off + (long)k * 128 + n;
    Wt[i] = bf ? ((const unsigned short*)W)[s] : f2us(((const float*)W)[s]);
}

// ---------- MFMA GEMM: C[M,128] = act(A[M,K] @ B[K,128] + bias) ----------
template <int C_BF>
__global__ __launch_bounds__(256) void mfma_gemm_kernel(const void* __restrict__ Ap, int a_input,
                                                        const unsigned short* __restrict__ Bt,
                                                        const void* __restrict__ bias, long bias_off,
                                                        void* __restrict__ Cp,
                                                        int M, int K, int do_relu,
                                                        const int* __restrict__ flagp) {
    __shared__ unsigned short As[128 * 40];
    __shared__ unsigned short Bs[128 * 40];
    const int bf = flagp[0];
    const int a_bf = a_input ? bf : 2;  // 2 == fp32 workspace
    const int t = threadIdx.x;
    const int bm = blockIdx.x * 128;
    const int lane = t & 63, wave = t >> 6;
    const int r = lane & 15, quad = lane >> 4;
    const int srow = t >> 1, skh = (t & 1) * 16;

    floatx4 acc[2][8];
#pragma unroll
    for (int mt = 0; mt < 2; ++mt)
#pragma unroll
        for (int nt = 0; nt < 8; ++nt)
#pragma unroll
            for (int q = 0; q < 4; ++q) acc[mt][nt][q] = 0.f;

    for (int k0 = 0; k0 < K; k0 += 32) {
        {
            const int grow = bm + srow;
            uint4 u0 = make_uint4(0, 0, 0, 0), u1 = u0;
            if (grow < M) {
                const long aidx = (long)grow * K + k0 + skh;
                if (a_bf == 1) {
                    const unsigned short* ap = (const unsigned short*)Ap + aidx;
                    u0 = ((const uint4*)ap)[0];
                    u1 = ((const uint4*)ap)[1];
                } else {
                    const float* ap = (const float*)Ap + aidx;
                    float4 f0 = ((const float4*)ap)[0];
                    float4 f1 = ((const float4*)ap)[1];
                    float4 f2 = ((const float4*)ap)[2];
                    float4 f3 = ((const float4*)ap)[3];
                    u0 = make_uint4(pack2(f0.x, f0.y), pack2(f0.z, f0.w), pack2(f1.x, f1.y), pack2(f1.z, f1.w));
                    u1 = make_uint4(pack2(f2.x, f2.y), pack2(f2.z, f2.w), pack2(f3.x, f3.y), pack2(f3.z, f3.w));
                }
            }
            *(uint4*)&As[srow * 40 + skh]     = u0;
            *(uint4*)&As[srow * 40 + skh + 8] = u1;
        }
        {
            const unsigned short* bp = Bt + (long)srow * K + k0 + skh;
            uint4 v0 = ((const uint4*)bp)[0];
            uint4 v1 = ((const uint4*)bp)[1];
            *(uint4*)&Bs[srow * 40 + skh]     = v0;
            *(uint4*)&Bs[srow * 40 + skh + 8] = v1;
        }
        __syncthreads();

        short8 afr[2];
        afr[0] = *(const short8*)&As[(wave * 32 + r) * 40 + quad * 8];
        afr[1] = *(const short8*)&As[(wave * 32 + 16 + r) * 40 + quad * 8];
#pragma unroll
        for (int nt = 0; nt < 8; ++nt) {
            short8 bfr = *(const short8*)&Bs[(nt * 16 + r) * 40 + quad * 8];
            acc[0][nt] = __builtin_amdgcn_mfma_f32_16x16x32_bf16(afr[0], bfr, acc[0][nt], 0, 0, 0);
            acc[1][nt] = __builtin_amdgcn_mfma_f32_16x16x32_bf16(afr[1], bfr, acc[1][nt], 0, 0, 0);
        }
        __syncthreads();
    }

    float bb[8];
#pragma unroll
    for (int nt = 0; nt < 8; ++nt) bb[nt] = bias ? ldw(bias, bias_off + nt * 16 + r, bf) : 0.f;

#pragma unroll
    for (int mt = 0; mt < 2; ++mt) {
        const int gr0 = bm + wave * 32 + mt * 16 + quad * 4;
#pragma unroll
        for (int reg = 0; reg < 4; ++reg) {
            const int grow = gr0 + reg;
            if (grow < M) {
#pragma unroll
                for (int nt = 0; nt < 8; ++nt) {
                    float v = acc[mt][nt][reg] + bb[nt];
                    if (do_relu) v = fmaxf(v, 0.f);
                    const long ci = (long)grow * HID + nt * 16 + r;
                    if (C_BF) ((unsigned short*)Cp)[ci] = f2us(v);
                    else      ((float*)Cp)[ci] = v;
                }
            }
        }
    }
}

// ---------- per-node attention scalars ----------
__global__ __launch_bounds__(256) void attn_kernel(const unsigned short* __restrict__ hp,
                                                   const void* __restrict__ att_src,
                                                   const void* __restrict__ att_dst, long a_off,
                                                   float* __restrict__ asrc, float* __restrict__ adst,
                                                   int N, const int* __restrict__ flagp) {
    __shared__ float sA[128], sD[128];
    const int bf = flagp[0];
    const int t = threadIdx.x;
    if (t < 128) { sA[t] = ldw(att_src, a_off + t, bf); sD[t] = ldw(att_dst, a_off + t, bf); }
    __syncthreads();
    const int gid = blockIdx.x * 256 + t;
    if (gid >= N * 4) return;
    const int n = gid >> 2, hd = gid & 3;
    const unsigned short* p = hp + (size_t)n * HID + hd * 32;
    float s1 = 0.f, s2 = 0.f;
#pragma unroll
    for (int q = 0; q < 4; ++q) {
        uint4 v = ((const uint4*)p)[q];
        unsigned arr[4] = {v.x, v.y, v.z, v.w};
#pragma unroll
        for (int j = 0; j < 4; ++j) {
            const int k = q * 8 + j * 2;
            float lo = lo2f(arr[j]);
            float hi = hi2f(arr[j]);
            s1 += lo * sA[hd * 32 + k] + hi * sA[hd * 32 + k + 1];
            s2 += lo * sD[hd * 32 + k] + hi * sD[hd * 32 + k + 1];
        }
    }
    asrc[gid] = s1;
    adst[gid] = s2;
}

// ---------- GAT aggregate + bias + LN + ReLU + residual (one wave per dst node) ----------
// Fast path (deg<=64): logits in registers, {src,weight} stashed in LDS (stride 5 -> conflict-free
// b64 broadcast reads), 4x-unrolled gather loop with 4 independent accumulator chains.
__global__ __launch_bounds__(256) void gat_kernel(float* __restrict__ h,
                                                  const unsigned short* __restrict__ hp,
                                                  const float* __restrict__ asrc,
                                                  const float* __restrict__ adst,
                                                  const int* __restrict__ row_ptr,
                                                  const int* __restrict__ csr,
                                                  const void* __restrict__ bgat,
                                                  const void* __restrict__ lng,
                                                  const void* __restrict__ lnb, long w_off,
                                                  int N, const int* __restrict__ flagp) {
    __shared__ uint2 ebuf[4][320];
    const int bf = flagp[0];
    const int lane = threadIdx.x & 63;
    const int wslot = threadIdx.x >> 6;
    const int head = lane >> 4;
    const int n = (blockIdx.x << 2) | wslot;
    if (n >= N) return;

    const int e0 = row_ptr[n], e1 = row_ptr[n + 1];
    const int d = e1 - e0;
    const float4 ad4 = *(const float4*)(adst + (size_t)n * 4);
    const float4 as4 = *(const float4*)(asrc + (size_t)n * 4);
    float4 es;
    es.x = lrelu(as4.x + ad4.x); es.y = lrelu(as4.y + ad4.y);
    es.z = lrelu(as4.z + ad4.z); es.w = lrelu(as4.w + ad4.w);

    float2 acc;
    float4 dn, exs;
    const int l2 = lane * 2;

    if (d <= 64) {
        // ---- fast path ----
        int s = 0;
        float4 l4 = es;
        if (lane < d) {
            s = csr[e0 + lane];
            const float4 a = *(const float4*)(asrc + (size_t)s * 4);
            l4.x = lrelu(a.x + ad4.x);
            l4.y = lrelu(a.y + ad4.y);
            l4.z = lrelu(a.z + ad4.z);
            l4.w = lrelu(a.w + ad4.w);
        }
        float4 m;
        m.x = fmaxf(wmaxr(l4.x), es.x);
        m.y = fmaxf(wmaxr(l4.y), es.y);
        m.z = fmaxf(wmaxr(l4.z), es.z);
        m.w = fmaxf(wmaxr(l4.w), es.w);

        exs.x = expf(es.x - m.x); exs.y = expf(es.y - m.y);
        exs.z = expf(es.z - m.z); exs.w = expf(es.w - m.w);

        float4 ex4 = make_float4(0.f, 0.f, 0.f, 0.f);
        if (lane < d) {
            ex4.x = expf(l4.x - m.x);
            ex4.y = expf(l4.y - m.y);
            ex4.z = expf(l4.z - m.z);
            ex4.w = expf(l4.w - m.w);
        }
        dn.x = wsum(ex4.x) + exs.x;
        dn.y = wsum(ex4.y) + exs.y;
        dn.z = wsum(ex4.z) + exs.z;
        dn.w = wsum(ex4.w) + exs.w;

        uint2* eb = ebuf[wslot];
        const unsigned su = (unsigned)s;
        eb[lane * 5 + 0] = make_uint2(su, __float_as_uint(ex4.x));
        eb[lane * 5 + 1] = make_uint2(su, __float_as_uint(ex4.y));
        eb[lane * 5 + 2] = make_uint2(su, __float_as_uint(ex4.z));
        eb[lane * 5 + 3] = make_uint2(su, __float_as_uint(ex4.w));

        const float wself = pick4(exs, head);
        const unsigned hv0 = *(const unsigned*)(hp + (size_t)n * HID + l2);
        acc.x = wself * lo2f(hv0);
        acc.y = wself * hi2f(hv0);

        float2 a0 = {0.f, 0.f}, a1 = {0.f, 0.f}, a2 = {0.f, 0.f}, a3 = {0.f, 0.f};
        int i = 0;
        for (; i + 4 <= d; i += 4) {
            const uint2 q0 = eb[(i + 0) * 5 + head];
            const uint2 q1 = eb[(i + 1) * 5 + head];
            const uint2 q2 = eb[(i + 2) * 5 + head];
            const uint2 q3 = eb[(i + 3) * 5 + head];
            const unsigned u0 = *(const unsigned*)(hp + (size_t)q0.x * HID + l2);
            const unsigned u1 = *(const unsigned*)(hp + (size_t)q1.x * HID + l2);
            const unsigned u2 = *(const unsigned*)(hp + (size_t)q2.x * HID + l2);
            const unsigned u3 = *(const unsigned*)(hp + (size_t)q3.x * HID + l2);
            const float w0 = __uint_as_float(q0.y);
            const float w1 = __uint_as_float(q1.y);
            const float w2 = __uint_as_float(q2.y);
            const float w3 = __uint_as_float(q3.y);
            a0.x = fmaf(w0, lo2f(u0), a0.x); a0.y = fmaf(w0, hi2f(u0), a0.y);
            a1.x = fmaf(w1, lo2f(u1), a1.x); a1.y = fmaf(w1, hi2f(u1), a1.y);
            a2.x = fmaf(w2, lo2f(u2), a2.x); a2.y = fmaf(w2, hi2f(u2), a2.y);
            a3.x = fmaf(w3, lo2f(u3), a3.x); a3.y = fmaf(w3, hi2f(u3), a3.y);
        }
        for (; i < d; ++i) {
            const uint2 q = eb[i * 5 + head];
            const unsigned u = *(const unsigned*)(hp + (size_t)q.x * HID + l2);
            const float wq = __uint_as_float(q.y);
            acc.x = fmaf(wq, lo2f(u), acc.x);
            acc.y = fmaf(wq, hi2f(u), acc.y);
        }
        acc.x += (a0.x + a1.x) + (a2.x + a3.x);
        acc.y += (a0.y + a1.y) + (a2.y + a3.y);
    } else {
        // ---- slow path (deg > 64): chunked recompute with shuffles ----
        float4 m = es;
        for (int e = e0 + lane; e < e1; e += 64) {
            const int s = csr[e];
            const float4 a = *(const float4*)(asrc + (size_t)s * 4);
            m.x = fmaxf(m.x, lrelu(a.x + ad4.x));
            m.y = fmaxf(m.y, lrelu(a.y + ad4.y));
            m.z = fmaxf(m.z, lrelu(a.z + ad4.z));
            m.w = fmaxf(m.w, lrelu(a.w + ad4.w));
        }
        m.x = wmaxr(m.x); m.y = wmaxr(m.y); m.z = wmaxr(m.z); m.w = wmaxr(m.w);

        exs.x = expf(es.x - m.x); exs.y = expf(es.y - m.y);
        exs.z = expf(es.z - m.z); exs.w = expf(es.w - m.w);

        const float wself = pick4(exs, head);
        const unsigned hv0 = *(const unsigned*)(hp + (size_t)n * HID + l2);
        acc.x = wself * lo2f(hv0);
        acc.y = wself * hi2f(hv0);
        dn = make_float4(0.f, 0.f, 0.f, 0.f);

        for (int base = e0; base < e1; base += 64) {
            const int cnt = min(64, e1 - base);
            int s = 0;
            float4 ex4 = make_float4(0.f, 0.f, 0.f, 0.f);
            if (base + lane < e1) {
                s = csr[base + lane];
                const float4 a = *(const float4*)(asrc + (size_t)s * 4);
                ex4.x = expf(lrelu(a.x + ad4.x) - m.x);
                ex4.y = expf(lrelu(a.y + ad4.y) - m.y);
                ex4.z = expf(lrelu(a.z + ad4.z) - m.z);
                ex4.w = expf(lrelu(a.w + ad4.w) - m.w);
                dn.x += ex4.x; dn.y += ex4.y; dn.z += ex4.z; dn.w += ex4.w;
            }
            for (int i = 0; i < cnt; ++i) {
                const int ss = __shfl(s, i);
                const float wx = __shfl(ex4.x, i);
                const float wy = __shfl(ex4.y, i);
                const float wz = __shfl(ex4.z, i);
                const float ww = __shfl(ex4.w, i);
                const float wgt = head == 0 ? wx : (head == 1 ? wy : (head == 2 ? wz : ww));
                const unsigned uv = *(const unsigned*)(hp + (size_t)ss * HID + l2);
                acc.x = fmaf(wgt, lo2f(uv), acc.x);
                acc.y = fmaf(wgt, hi2f(uv), acc.y);
            }
        }
        dn.x = wsum(dn.x) + exs.x;
        dn.y = wsum(dn.y) + exs.y;
        dn.z = wsum(dn.z) + exs.z;
        dn.w = wsum(dn.w) + exs.w;
    }

    const float invd = 1.f / fmaxf(pick4(dn, head), 1e-16f);
    acc.x *= invd; acc.y *= invd;
    acc.x += ldw(bgat, w_off + l2, bf);
    acc.y += ldw(bgat, w_off + l2 + 1, bf);

    float mean = wsum(acc.x + acc.y) * (1.f / 128.f);
    float dx = acc.x - mean, dy = acc.y - mean;
    float var = wsum(dx * dx + dy * dy) * (1.f / 128.f);
    float rstd = rsqrtf(var + LN_EPS);
    float o0 = dx * rstd * ldw(lng, w_off + l2, bf)     + ldw(lnb, w_off + l2, bf);
    float o1 = dy * rstd * ldw(lng, w_off + l2 + 1, bf) + ldw(lnb, w_off + l2 + 1, bf);
    o0 = fmaxf(o0, 0.f);
    o1 = fmaxf(o1, 0.f);

    const float2 r = *(const float2*)(h + (size_t)n * HID + l2);
    *(float2*)(h + (size_t)n * HID + l2) = make_float2(o0 + r.x, o1 + r.y);
}

// ---------- pooling (sorted batch -> contiguous ranges, no atomics) ----------
__global__ __launch_bounds__(256) void pool_kernel(const float* __restrict__ h, const int* __restrict__ batch,
                                                   void* __restrict__ out, int N,
                                                   const int* __restrict__ flagp) {
    const int g = blockIdx.x;
    int a = 0, b = N;
    while (a < b) { int mid = (a + b) >> 1; if (batch[mid] < g) a = mid + 1; else b = mid; }
    const int lo = a;
    b = N;
    while (a < b) { int mid = (a + b) >> 1; if (batch[mid] <= g) a = mid + 1; else b = mid; }
    const int hi = a;

    const int col = threadIdx.x & 127;
    const int half = threadIdx.x >> 7;
    float s = 0.f;
    for (int r = lo + half; r < hi; r += 2) s += h[(size_t)r * HID + col];
    __shared__ float part[128];
    if (half == 0) part[col] = s;
    __syncthreads();
    if (half == 1) {
        const float tot = part[col] + s;
        const float v = tot / fmaxf((float)(hi - lo), 1.f);
        if (flagp[0]) ((unsigned short*)out)[g * HID + col] = f2us(v);
        else          ((float*)out)[g * HID + col] = v;
    }
}

// ---------- launch ----------
extern "C" void kernel_launch(void* const* d_in, const int* in_sizes, int n_in,
                              void* d_out, int out_size, void* d_ws, size_t ws_size,
                              hipStream_t stream) {
    const void* x     = d_in[0];
    const void* W_in  = d_in[1];
    const void* b_in  = d_in[2];
    const void* W_gat = d_in[3];
    const void* att_s = d_in[4];
    const void* att_d = d_in[5];
    const void* b_gat = d_in[6];
    const void* ln_g  = d_in[7];
    const void* ln_b  = d_in[8];
    const int* edge_index = (const int*)d_in[9];
    const int* batch      = (const int*)d_in[10];

    const int N = in_sizes[10];
    const int E = in_sizes[9] / 2;
    const int IN_DIM = in_sizes[0] / N;
    const int n_graphs = out_size / HID;

    const int* esrc = edge_index;
    const int* edst = edge_index + E;

    char* w = (char*)d_ws;
    auto carve = [&](size_t bytes) -> void* {
        void* p = (void*)w;
        w += (bytes + 255) & ~(size_t)255;
        return p;
    };
    int* flag            = (int*)carve(256);
    int* row_ptr         = (int*)carve((size_t)(N + 1) * 4);
    int* cursor          = (int*)carve((size_t)N * 4);
    int* csr             = (int*)carve((size_t)E * 4);
    float* asrc          = (float*)carve((size_t)N * 4 * 4);
    float* adst          = (float*)carve((size_t)N * 4 * 4);
    unsigned short* Wt_in = (unsigned short*)carve((size_t)HID * IN_DIM * 2);
    unsigned short* Wt_g  = (unsigned short*)carve((size_t)HID * HID * 2);
    float* h             = (float*)carve((size_t)N * HID * 4);
    unsigned short* hp   = (unsigned short*)carve((size_t)N * HID * 2);
    (void)ws_size; (void)n_in;

    detect_kernel<<<1, 64, 0, stream>>>((const float*)x, flag);

    // CSR by destination
    zero_int_kernel<<<(N + 255) / 256, 256, 0, stream>>>(cursor, N);
    count_kernel<<<(E + 255) / 256, 256, 0, stream>>>(edst, E, cursor);
    scan_kernel<<<1, 1024, 0, stream>>>(cursor, row_ptr, N);
    copy_int_kernel<<<(N + 255) / 256, 256, 0, stream>>>(row_ptr, cursor, N);
    scatter_kernel<<<(E + 255) / 256, 256, 0, stream>>>(esrc, edst, E, cursor, csr);

    // input projection: h = relu(x @ W_in + b_in)
    transpose_w_kernel<<<(HID * IN_DIM + 255) / 256, 256, 0, stream>>>(W_in, 0, IN_DIM, Wt_in, flag);
    mfma_gemm_kernel<0><<<(N + 127) / 128, 256, 0, stream>>>(x, 1, Wt_in, b_in, 0, h, N, IN_DIM, 1, flag);

    for (int l = 0; l < 3; ++l) {
        transpose_w_kernel<<<(HID * HID + 255) / 256, 256, 0, stream>>>(W_gat, (long)l * HID * HID, HID, Wt_g, flag);
        mfma_gemm_kernel<1><<<(N + 127) / 128, 256, 0, stream>>>(h, 0, Wt_g, nullptr, 0, hp, N, HID, 0, flag);
        attn_kernel<<<(N * 4 + 255) / 256, 256, 0, stream>>>(hp, att_s, att_d, (long)l * HID,
                                                             asrc, adst, N, flag);
        gat_kernel<<<(N + 3) / 4, 256, 0, stream>>>(h, hp, asrc, adst, row_ptr, csr,
                                                    b_gat, ln_g, ln_b, (long)l * HID, N, flag);
    }

    pool_kernel<<<n_graphs, 256, 0, stream>>>(h, batch, d_out, N, flag);
}

// Round 5
// 977.080 us; speedup vs baseline: 1.9593x; 1.1573x over previous
//
#include <hip/hip_runtime.h>
#include <hip/hip_bf16.h>

#define HID 128
#define NEG_SLOPE 0.2f
#define LN_EPS 1e-5f

typedef __attribute__((ext_vector_type(8))) short short8;
typedef __attribute__((ext_vector_type(4))) float floatx4;

// ---------- helpers ----------
__device__ __forceinline__ float us2f(unsigned short u) {
    union { unsigned int i; float f; } c; c.i = ((unsigned int)u) << 16; return c.f;
}
__device__ __forceinline__ float lo2f(unsigned u) {
    union { unsigned int i; float f; } c; c.i = u << 16; return c.f;
}
__device__ __forceinline__ float hi2f(unsigned u) {
    union { unsigned int i; float f; } c; c.i = u & 0xffff0000u; return c.f;
}
__device__ __forceinline__ unsigned short f2us(float f) {  // RNE bf16 pack
    union { float f; unsigned u; } c; c.f = f;
    unsigned r = c.u + 0x7FFF + ((c.u >> 16) & 1);
    return (unsigned short)(r >> 16);
}
__device__ __forceinline__ unsigned pack2(float a, float b) {
    return (unsigned)f2us(a) | ((unsigned)f2us(b) << 16);
}
__device__ __forceinline__ float ldw(const void* p, long i, int bf) {
    return bf ? us2f(((const unsigned short*)p)[i]) : ((const float*)p)[i];
}
__device__ __forceinline__ float lrelu(float x) { return x > 0.f ? x : NEG_SLOPE * x; }
__device__ __forceinline__ float wsum(float x) {
#pragma unroll
    for (int o = 32; o > 0; o >>= 1) x += __shfl_xor(x, o);
    return x;
}
__device__ __forceinline__ int wsumi(int x) {
#pragma unroll
    for (int o = 32; o > 0; o >>= 1) x += __shfl_xor(x, o);
    return x;
}
__device__ __forceinline__ float wmaxr(float x) {
#pragma unroll
    for (int o = 32; o > 0; o >>= 1) x = fmaxf(x, __shfl_xor(x, o));
    return x;
}
__device__ __forceinline__ float pick4(float4 v, int h) {
    return h == 0 ? v.x : (h == 1 ? v.y : (h == 2 ? v.z : v.w));
}

// ---------- dtype sniff ----------
__global__ void detect_kernel(const float* __restrict__ x, int* __restrict__ flag) {
    float v = x[threadIdx.x];
    int bad = (!(v == v)) || (fabsf(v) > 1e6f);
    unsigned long long m = __ballot(bad);
    if (threadIdx.x == 0) flag[0] = (m != 0ull) ? 1 : 0;
}

// ---------- CSR build ----------
__global__ __launch_bounds__(256) void zero_int_kernel(int* p, int n) {
    int i = blockIdx.x * 256 + threadIdx.x;
    if (i < n) p[i] = 0;
}
__global__ __launch_bounds__(256) void count_kernel(const int* __restrict__ dst, int E, int* __restrict__ deg) {
    int e = blockIdx.x * 256 + threadIdx.x;
    if (e < E) atomicAdd(&deg[dst[e]], 1);
}

// hierarchical exclusive scan of deg[N] -> row_ptr[N+1]; 1024 elems/block, nb = ceil(N/1024) <= 256
__global__ __launch_bounds__(256) void bsum_kernel(const int* __restrict__ deg, int* __restrict__ bsum, int N) {
    __shared__ int red[4];
    const int base = blockIdx.x * 1024 + threadIdx.x * 4;
    int s = 0;
    if (base + 3 < N) {
        int4 v = *(const int4*)(deg + base);
        s = v.x + v.y + v.z + v.w;
    } else {
#pragma unroll
        for (int i = 0; i < 4; ++i) if (base + i < N) s += deg[base + i];
    }
    s = wsumi(s);
    if ((threadIdx.x & 63) == 0) red[threadIdx.x >> 6] = s;
    __syncthreads();
    if (threadIdx.x == 0) bsum[blockIdx.x] = red[0] + red[1] + red[2] + red[3];
}
__global__ __launch_bounds__(256) void bscan_kernel(const int* __restrict__ bsum, int* __restrict__ boff,
                                                    int* __restrict__ row_ptr, int nb, int N) {
    __shared__ int sc[256];
    const int t = threadIdx.x;
    const int v = (t < nb) ? bsum[t] : 0;
    int x = v;
    sc[t] = x;
    __syncthreads();
    for (int o = 1; o < 256; o <<= 1) {
        const int y = (t >= o) ? sc[t - o] : 0;
        __syncthreads();
        x += y;
        sc[t] = x;
        __syncthreads();
    }
    if (t < nb) boff[t] = x - v;        // exclusive block offset
    if (t == nb - 1) row_ptr[N] = x;    // total
}
__global__ __launch_bounds__(256) void rscan_kernel(const int* __restrict__ deg, const int* __restrict__ boff,
                                                    int* __restrict__ row_ptr, int N) {
    __shared__ int sc[256];
    const int t = threadIdx.x;
    const int base = blockIdx.x * 1024 + t * 4;
    int d0 = 0, d1 = 0, d2 = 0, d3 = 0;
    if (base + 3 < N) {
        int4 v = *(const int4*)(deg + base);
        d0 = v.x; d1 = v.y; d2 = v.z; d3 = v.w;
    } else {
        if (base + 0 < N) d0 = deg[base + 0];
        if (base + 1 < N) d1 = deg[base + 1];
        if (base + 2 < N) d2 = deg[base + 2];
        if (base + 3 < N) d3 = deg[base + 3];
    }
    const int tot = d0 + d1 + d2 + d3;
    int x = tot;
    sc[t] = x;
    __syncthreads();
    for (int o = 1; o < 256; o <<= 1) {
        const int y = (t >= o) ? sc[t - o] : 0;
        __syncthreads();
        x += y;
        sc[t] = x;
        __syncthreads();
    }
    const int off = boff[blockIdx.x] + x - tot;
    if (base + 0 < N) row_ptr[base + 0] = off;
    if (base + 1 < N) row_ptr[base + 1] = off + d0;
    if (base + 2 < N) row_ptr[base + 2] = off + d0 + d1;
    if (base + 3 < N) row_ptr[base + 3] = off + d0 + d1 + d2;
}

__global__ __launch_bounds__(256) void copy_int_kernel(const int* __restrict__ a, int* __restrict__ b, int n) {
    int i = blockIdx.x * 256 + threadIdx.x;
    if (i < n) b[i] = a[i];
}
__global__ __launch_bounds__(256) void scatter_kernel(const int* __restrict__ src, const int* __restrict__ dst,
                                                      int E, int* __restrict__ cursor, int* __restrict__ csr) {
    int e = blockIdx.x * 256 + threadIdx.x;
    if (e < E) {
        int p = atomicAdd(&cursor[dst[e]], 1);
        csr[p] = src[e];
    }
}

// ---------- W transpose+convert: Wt[n][k] = bf16(W[w_off + k*128 + n]) ----------
__global__ __launch_bounds__(256) void transpose_w_kernel(const void* __restrict__ W, long w_off, int K,
                                                          unsigned short* __restrict__ Wt,
                                                          const int* __restrict__ flagp) {
    const int bf = flagp[0];
    const int i = blockIdx.x * 256 + threadIdx.x;
    if (i >= 128 * K) return;
    const int n = i / K, k = i - n * K;
    const long s = w_off + (long)k * 128 + n;
    Wt[i] = bf ? ((const unsigned short*)W)[s] : f2us(((const float*)W)[s]);
}

// ---------- MFMA GEMM: C[M,128] = act(A[M,K] @ B[K,128] + bias) ----------
template <int C_BF>
__global__ __launch_bounds__(256) void mfma_gemm_kernel(const void* __restrict__ Ap, int a_input,
                                                        const unsigned short* __restrict__ Bt,
                                                        const void* __restrict__ bias, long bias_off,
                                                        void* __restrict__ Cp,
                                                        int M, int K, int do_relu,
                                                        const int* __restrict__ flagp) {
    __shared__ unsigned short As[128 * 40];
    __shared__ unsigned short Bs[128 * 40];
    const int bf = flagp[0];
    const int a_bf = a_input ? bf : 2;  // 2 == fp32 workspace
    const int t = threadIdx.x;
    const int bm = blockIdx.x * 128;
    const int lane = t & 63, wave = t >> 6;
    const int r = lane & 15, quad = lane >> 4;
    const int srow = t >> 1, skh = (t & 1) * 16;

    floatx4 acc[2][8];
#pragma unroll
    for (int mt = 0; mt < 2; ++mt)
#pragma unroll
        for (int nt = 0; nt < 8; ++nt)
#pragma unroll
            for (int q = 0; q < 4; ++q) acc[mt][nt][q] = 0.f;

    for (int k0 = 0; k0 < K; k0 += 32) {
        {
            const int grow = bm + srow;
            uint4 u0 = make_uint4(0, 0, 0, 0), u1 = u0;
            if (grow < M) {
                const long aidx = (long)grow * K + k0 + skh;
                if (a_bf == 1) {
                    const unsigned short* ap = (const unsigned short*)Ap + aidx;
                    u0 = ((const uint4*)ap)[0];
                    u1 = ((const uint4*)ap)[1];
                } else {
                    const float* ap = (const float*)Ap + aidx;
                    float4 f0 = ((const float4*)ap)[0];
                    float4 f1 = ((const float4*)ap)[1];
                    float4 f2 = ((const float4*)ap)[2];
                    float4 f3 = ((const float4*)ap)[3];
                    u0 = make_uint4(pack2(f0.x, f0.y), pack2(f0.z, f0.w), pack2(f1.x, f1.y), pack2(f1.z, f1.w));
                    u1 = make_uint4(pack2(f2.x, f2.y), pack2(f2.z, f2.w), pack2(f3.x, f3.y), pack2(f3.z, f3.w));
                }
            }
            *(uint4*)&As[srow * 40 + skh]     = u0;
            *(uint4*)&As[srow * 40 + skh + 8] = u1;
        }
        {
            const unsigned short* bp = Bt + (long)srow * K + k0 + skh;
            uint4 v0 = ((const uint4*)bp)[0];
            uint4 v1 = ((const uint4*)bp)[1];
            *(uint4*)&Bs[srow * 40 + skh]     = v0;
            *(uint4*)&Bs[srow * 40 + skh + 8] = v1;
        }
        __syncthreads();

        short8 afr[2];
        afr[0] = *(const short8*)&As[(wave * 32 + r) * 40 + quad * 8];
        afr[1] = *(const short8*)&As[(wave * 32 + 16 + r) * 40 + quad * 8];
#pragma unroll
        for (int nt = 0; nt < 8; ++nt) {
            short8 bfr = *(const short8*)&Bs[(nt * 16 + r) * 40 + quad * 8];
            acc[0][nt] = __builtin_amdgcn_mfma_f32_16x16x32_bf16(afr[0], bfr, acc[0][nt], 0, 0, 0);
            acc[1][nt] = __builtin_amdgcn_mfma_f32_16x16x32_bf16(afr[1], bfr, acc[1][nt], 0, 0, 0);
        }
        __syncthreads();
    }

    float bb[8];
#pragma unroll
    for (int nt = 0; nt < 8; ++nt) bb[nt] = bias ? ldw(bias, bias_off + nt * 16 + r, bf) : 0.f;

#pragma unroll
    for (int mt = 0; mt < 2; ++mt) {
        const int gr0 = bm + wave * 32 + mt * 16 + quad * 4;
#pragma unroll
        for (int reg = 0; reg < 4; ++reg) {
            const int grow = gr0 + reg;
            if (grow < M) {
#pragma unroll
                for (int nt = 0; nt < 8; ++nt) {
                    float v = acc[mt][nt][reg] + bb[nt];
                    if (do_relu) v = fmaxf(v, 0.f);
                    const long ci = (long)grow * HID + nt * 16 + r;
                    if (C_BF) ((unsigned short*)Cp)[ci] = f2us(v);
                    else      ((float*)Cp)[ci] = v;
                }
            }
        }
    }
}

// ---------- per-node attention scalars ----------
__global__ __launch_bounds__(256) void attn_kernel(const unsigned short* __restrict__ hp,
                                                   const void* __restrict__ att_src,
                                                   const void* __restrict__ att_dst, long a_off,
                                                   float* __restrict__ asrc, float* __restrict__ adst,
                                                   int N, const int* __restrict__ flagp) {
    __shared__ float sA[128], sD[128];
    const int bf = flagp[0];
    const int t = threadIdx.x;
    if (t < 128) { sA[t] = ldw(att_src, a_off + t, bf); sD[t] = ldw(att_dst, a_off + t, bf); }
    __syncthreads();
    const int gid = blockIdx.x * 256 + t;
    if (gid >= N * 4) return;
    const int n = gid >> 2, hd = gid & 3;
    const unsigned short* p = hp + (size_t)n * HID + hd * 32;
    float s1 = 0.f, s2 = 0.f;
#pragma unroll
    for (int q = 0; q < 4; ++q) {
        uint4 v = ((const uint4*)p)[q];
        unsigned arr[4] = {v.x, v.y, v.z, v.w};
#pragma unroll
        for (int j = 0; j < 4; ++j) {
            const int k = q * 8 + j * 2;
            float lo = lo2f(arr[j]);
            float hi = hi2f(arr[j]);
            s1 += lo * sA[hd * 32 + k] + hi * sA[hd * 32 + k + 1];
            s2 += lo * sD[hd * 32 + k] + hi * sD[hd * 32 + k + 1];
        }
    }
    asrc[gid] = s1;
    adst[gid] = s2;
}

// ---------- GAT aggregate + bias + LN + ReLU + residual (one wave per dst node) ----------
__global__ __launch_bounds__(256) void gat_kernel(float* __restrict__ h,
                                                  const unsigned short* __restrict__ hp,
                                                  const float* __restrict__ asrc,
                                                  const float* __restrict__ adst,
                                                  const int* __restrict__ row_ptr,
                                                  const int* __restrict__ csr,
                                                  const void* __restrict__ bgat,
                                                  const void* __restrict__ lng,
                                                  const void* __restrict__ lnb, long w_off,
                                                  int N, const int* __restrict__ flagp) {
    __shared__ uint2 ebuf[4][320];
    const int bf = flagp[0];
    const int lane = threadIdx.x & 63;
    const int wslot = threadIdx.x >> 6;
    const int head = lane >> 4;
    const int n = (blockIdx.x << 2) | wslot;
    if (n >= N) return;

    const int e0 = row_ptr[n], e1 = row_ptr[n + 1];
    const int d = e1 - e0;
    const float4 ad4 = *(const float4*)(adst + (size_t)n * 4);
    const float4 as4 = *(const float4*)(asrc + (size_t)n * 4);
    float4 es;
    es.x = lrelu(as4.x + ad4.x); es.y = lrelu(as4.y + ad4.y);
    es.z = lrelu(as4.z + ad4.z); es.w = lrelu(as4.w + ad4.w);

    float2 acc;
    float4 dn, exs;
    const int l2 = lane * 2;

    if (d <= 64) {
        // ---- fast path ----
        int s = 0;
        float4 l4 = es;
        if (lane < d) {
            s = csr[e0 + lane];
            const float4 a = *(const float4*)(asrc + (size_t)s * 4);
            l4.x = lrelu(a.x + ad4.x);
            l4.y = lrelu(a.y + ad4.y);
            l4.z = lrelu(a.z + ad4.z);
            l4.w = lrelu(a.w + ad4.w);
        }
        float4 m;
        m.x = fmaxf(wmaxr(l4.x), es.x);
        m.y = fmaxf(wmaxr(l4.y), es.y);
        m.z = fmaxf(wmaxr(l4.z), es.z);
        m.w = fmaxf(wmaxr(l4.w), es.w);

        exs.x = expf(es.x - m.x); exs.y = expf(es.y - m.y);
        exs.z = expf(es.z - m.z); exs.w = expf(es.w - m.w);

        float4 ex4 = make_float4(0.f, 0.f, 0.f, 0.f);
        if (lane < d) {
            ex4.x = expf(l4.x - m.x);
            ex4.y = expf(l4.y - m.y);
            ex4.z = expf(l4.z - m.z);
            ex4.w = expf(l4.w - m.w);
        }
        dn.x = wsum(ex4.x) + exs.x;
        dn.y = wsum(ex4.y) + exs.y;
        dn.z = wsum(ex4.z) + exs.z;
        dn.w = wsum(ex4.w) + exs.w;

        uint2* eb = ebuf[wslot];
        const unsigned su = (unsigned)s;
        eb[lane * 5 + 0] = make_uint2(su, __float_as_uint(ex4.x));
        eb[lane * 5 + 1] = make_uint2(su, __float_as_uint(ex4.y));
        eb[lane * 5 + 2] = make_uint2(su, __float_as_uint(ex4.z));
        eb[lane * 5 + 3] = make_uint2(su, __float_as_uint(ex4.w));

        const float wself = pick4(exs, head);
        const unsigned hv0 = *(const unsigned*)(hp + (size_t)n * HID + l2);
        acc.x = wself * lo2f(hv0);
        acc.y = wself * hi2f(hv0);

        float2 a0 = {0.f, 0.f}, a1 = {0.f, 0.f}, a2 = {0.f, 0.f}, a3 = {0.f, 0.f};
        int i = 0;
        for (; i + 4 <= d; i += 4) {
            const uint2 q0 = eb[(i + 0) * 5 + head];
            const uint2 q1 = eb[(i + 1) * 5 + head];
            const uint2 q2 = eb[(i + 2) * 5 + head];
            const uint2 q3 = eb[(i + 3) * 5 + head];
            const unsigned u0 = *(const unsigned*)(hp + (size_t)q0.x * HID + l2);
            const unsigned u1 = *(const unsigned*)(hp + (size_t)q1.x * HID + l2);
            const unsigned u2 = *(const unsigned*)(hp + (size_t)q2.x * HID + l2);
            const unsigned u3 = *(const unsigned*)(hp + (size_t)q3.x * HID + l2);
            const float w0 = __uint_as_float(q0.y);
            const float w1 = __uint_as_float(q1.y);
            const float w2 = __uint_as_float(q2.y);
            const float w3 = __uint_as_float(q3.y);
            a0.x = fmaf(w0, lo2f(u0), a0.x); a0.y = fmaf(w0, hi2f(u0), a0.y);
            a1.x = fmaf(w1, lo2f(u1), a1.x); a1.y = fmaf(w1, hi2f(u1), a1.y);
            a2.x = fmaf(w2, lo2f(u2), a2.x); a2.y = fmaf(w2, hi2f(u2), a2.y);
            a3.x = fmaf(w3, lo2f(u3), a3.x); a3.y = fmaf(w3, hi2f(u3), a3.y);
        }
        for (; i < d; ++i) {
            const uint2 q = eb[i * 5 + head];
            const unsigned u = *(const unsigned*)(hp + (size_t)q.x * HID + l2);
            const float wq = __uint_as_float(q.y);
            acc.x = fmaf(wq, lo2f(u), acc.x);
            acc.y = fmaf(wq, hi2f(u), acc.y);
        }
        acc.x += (a0.x + a1.x) + (a2.x + a3.x);
        acc.y += (a0.y + a1.y) + (a2.y + a3.y);
    } else {
        // ---- slow path (deg > 64) ----
        float4 m = es;
        for (int e = e0 + lane; e < e1; e += 64) {
            const int s = csr[e];
            const float4 a = *(const float4*)(asrc + (size_t)s * 4);
            m.x = fmaxf(m.x, lrelu(a.x + ad4.x));
            m.y = fmaxf(m.y, lrelu(a.y + ad4.y));
            m.z = fmaxf(m.z, lrelu(a.z + ad4.z));
            m.w = fmaxf(m.w, lrelu(a.w + ad4.w));
        }
        m.x = wmaxr(m.x); m.y = wmaxr(m.y); m.z = wmaxr(m.z); m.w = wmaxr(m.w);

        exs.x = expf(es.x - m.x); exs.y = expf(es.y - m.y);
        exs.z = expf(es.z - m.z); exs.w = expf(es.w - m.w);

        const float wself = pick4(exs, head);
        const unsigned hv0 = *(const unsigned*)(hp + (size_t)n * HID + l2);
        acc.x = wself * lo2f(hv0);
        acc.y = wself * hi2f(hv0);
        dn = make_float4(0.f, 0.f, 0.f, 0.f);

        for (int base = e0; base < e1; base += 64) {
            const int cnt = min(64, e1 - base);
            int s = 0;
            float4 ex4 = make_float4(0.f, 0.f, 0.f, 0.f);
            if (base + lane < e1) {
                s = csr[base + lane];
                const float4 a = *(const float4*)(asrc + (size_t)s * 4);
                ex4.x = expf(lrelu(a.x + ad4.x) - m.x);
                ex4.y = expf(lrelu(a.y + ad4.y) - m.y);
                ex4.z = expf(lrelu(a.z + ad4.z) - m.z);
                ex4.w = expf(lrelu(a.w + ad4.w) - m.w);
                dn.x += ex4.x; dn.y += ex4.y; dn.z += ex4.z; dn.w += ex4.w;
            }
            for (int i = 0; i < cnt; ++i) {
                const int ss = __shfl(s, i);
                const float wx = __shfl(ex4.x, i);
                const float wy = __shfl(ex4.y, i);
                const float wz = __shfl(ex4.z, i);
                const float ww = __shfl(ex4.w, i);
                const float wgt = head == 0 ? wx : (head == 1 ? wy : (head == 2 ? wz : ww));
                const unsigned uv = *(const unsigned*)(hp + (size_t)ss * HID + l2);
                acc.x = fmaf(wgt, lo2f(uv), acc.x);
                acc.y = fmaf(wgt, hi2f(uv), acc.y);
            }
        }
        dn.x = wsum(dn.x) + exs.x;
        dn.y = wsum(dn.y) + exs.y;
        dn.z = wsum(dn.z) + exs.z;
        dn.w = wsum(dn.w) + exs.w;
    }

    const float invd = 1.f / fmaxf(pick4(dn, head), 1e-16f);
    acc.x *= invd; acc.y *= invd;
    acc.x += ldw(bgat, w_off + l2, bf);
    acc.y += ldw(bgat, w_off + l2 + 1, bf);

    float mean = wsum(acc.x + acc.y) * (1.f / 128.f);
    float dx = acc.x - mean, dy = acc.y - mean;
    float var = wsum(dx * dx + dy * dy) * (1.f / 128.f);
    float rstd = rsqrtf(var + LN_EPS);
    float o0 = dx * rstd * ldw(lng, w_off + l2, bf)     + ldw(lnb, w_off + l2, bf);
    float o1 = dy * rstd * ldw(lng, w_off + l2 + 1, bf) + ldw(lnb, w_off + l2 + 1, bf);
    o0 = fmaxf(o0, 0.f);
    o1 = fmaxf(o1, 0.f);

    const float2 r = *(const float2*)(h + (size_t)n * HID + l2);
    *(float2*)(h + (size_t)n * HID + l2) = make_float2(o0 + r.x, o1 + r.y);
}

// ---------- pooling (sorted batch -> contiguous ranges, no atomics) ----------
__global__ __launch_bounds__(256) void pool_kernel(const float* __restrict__ h, const int* __restrict__ batch,
                                                   void* __restrict__ out, int N,
                                                   const int* __restrict__ flagp) {
    const int g = blockIdx.x;
    int a = 0, b = N;
    while (a < b) { int mid = (a + b) >> 1; if (batch[mid] < g) a = mid + 1; else b = mid; }
    const int lo = a;
    b = N;
    while (a < b) { int mid = (a + b) >> 1; if (batch[mid] <= g) a = mid + 1; else b = mid; }
    const int hi = a;

    const int col = threadIdx.x & 127;
    const int half = threadIdx.x >> 7;
    float s = 0.f;
    for (int r = lo + half; r < hi; r += 2) s += h[(size_t)r * HID + col];
    __shared__ float part[128];
    if (half == 0) part[col] = s;
    __syncthreads();
    if (half == 1) {
        const float tot = part[col] + s;
        const float v = tot / fmaxf((float)(hi - lo), 1.f);
        if (flagp[0]) ((unsigned short*)out)[g * HID + col] = f2us(v);
        else          ((float*)out)[g * HID + col] = v;
    }
}

// ---------- launch ----------
extern "C" void kernel_launch(void* const* d_in, const int* in_sizes, int n_in,
                              void* d_out, int out_size, void* d_ws, size_t ws_size,
                              hipStream_t stream) {
    const void* x     = d_in[0];
    const void* W_in  = d_in[1];
    const void* b_in  = d_in[2];
    const void* W_gat = d_in[3];
    const void* att_s = d_in[4];
    const void* att_d = d_in[5];
    const void* b_gat = d_in[6];
    const void* ln_g  = d_in[7];
    const void* ln_b  = d_in[8];
    const int* edge_index = (const int*)d_in[9];
    const int* batch      = (const int*)d_in[10];

    const int N = in_sizes[10];
    const int E = in_sizes[9] / 2;
    const int IN_DIM = in_sizes[0] / N;
    const int n_graphs = out_size / HID;

    const int* esrc = edge_index;
    const int* edst = edge_index + E;

    char* w = (char*)d_ws;
    auto carve = [&](size_t bytes) -> void* {
        void* p = (void*)w;
        w += (bytes + 255) & ~(size_t)255;
        return p;
    };
    int* flag            = (int*)carve(256);
    int* row_ptr         = (int*)carve((size_t)(N + 1) * 4);
    int* cursor          = (int*)carve((size_t)N * 4);
    int* csr             = (int*)carve((size_t)E * 4);
    float* asrc          = (float*)carve((size_t)N * 4 * 4);
    float* adst          = (float*)carve((size_t)N * 4 * 4);
    int* bsum            = (int*)carve(256 * 4);
    int* boff            = (int*)carve(256 * 4);
    unsigned short* Wt_in = (unsigned short*)carve((size_t)HID * IN_DIM * 2);
    unsigned short* Wt_g  = (unsigned short*)carve((size_t)HID * HID * 2);
    float* h             = (float*)carve((size_t)N * HID * 4);
    unsigned short* hp   = (unsigned short*)carve((size_t)N * HID * 2);
    (void)ws_size; (void)n_in;

    detect_kernel<<<1, 64, 0, stream>>>((const float*)x, flag);

    // CSR by destination (deg in `cursor`); hierarchical scan (nb <= 256 blocks of 1024)
    const int nb = (N + 1023) / 1024;
    zero_int_kernel<<<(N + 255) / 256, 256, 0, stream>>>(cursor, N);
    count_kernel<<<(E + 255) / 256, 256, 0, stream>>>(edst, E, cursor);
    bsum_kernel<<<nb, 256, 0, stream>>>(cursor, bsum, N);
    bscan_kernel<<<1, 256, 0, stream>>>(bsum, boff, row_ptr, nb, N);
    rscan_kernel<<<nb, 256, 0, stream>>>(cursor, boff, row_ptr, N);
    copy_int_kernel<<<(N + 255) / 256, 256, 0, stream>>>(row_ptr, cursor, N);
    scatter_kernel<<<(E + 255) / 256, 256, 0, stream>>>(esrc, edst, E, cursor, csr);

    // input projection: h = relu(x @ W_in + b_in)
    transpose_w_kernel<<<(HID * IN_DIM + 255) / 256, 256, 0, stream>>>(W_in, 0, IN_DIM, Wt_in, flag);
    mfma_gemm_kernel<0><<<(N + 127) / 128, 256, 0, stream>>>(x, 1, Wt_in, b_in, 0, h, N, IN_DIM, 1, flag);

    for (int l = 0; l < 3; ++l) {
        transpose_w_kernel<<<(HID * HID + 255) / 256, 256, 0, stream>>>(W_gat, (long)l * HID * HID, HID, Wt_g, flag);
        mfma_gemm_kernel<1><<<(N + 127) / 128, 256, 0, stream>>>(h, 0, Wt_g, nullptr, 0, hp, N, HID, 0, flag);
        attn_kernel<<<(N * 4 + 255) / 256, 256, 0, stream>>>(hp, att_s, att_d, (long)l * HID,
                                                             asrc, adst, N, flag);
        gat_kernel<<<(N + 3) / 4, 256, 0, stream>>>(h, hp, asrc, adst, row_ptr, csr,
                                                    b_gat, ln_g, ln_b, (long)l * HID, N, flag);
    }

    pool_kernel<<<n_graphs, 256, 0, stream>>>(h, batch, d_out, N, flag);
}

// Round 6
// 833.179 us; speedup vs baseline: 2.2977x; 1.1727x over previous
//
#include <hip/hip_runtime.h>
#include <hip/hip_bf16.h>

#define HID 128
#define NEG_SLOPE 0.2f
#define LN_EPS 1e-5f
#define SEG_CAP 8192   // max edges per 256-node bucket (mean 4096, sigma~64)

typedef __attribute__((ext_vector_type(8))) short short8;
typedef __attribute__((ext_vector_type(4))) float floatx4;

// ---------- helpers ----------
__device__ __forceinline__ float us2f(unsigned short u) {
    union { unsigned int i; float f; } c; c.i = ((unsigned int)u) << 16; return c.f;
}
__device__ __forceinline__ float lo2f(unsigned u) {
    union { unsigned int i; float f; } c; c.i = u << 16; return c.f;
}
__device__ __forceinline__ float hi2f(unsigned u) {
    union { unsigned int i; float f; } c; c.i = u & 0xffff0000u; return c.f;
}
__device__ __forceinline__ unsigned short f2us(float f) {  // RNE bf16 pack
    union { float f; unsigned u; } c; c.f = f;
    unsigned r = c.u + 0x7FFF + ((c.u >> 16) & 1);
    return (unsigned short)(r >> 16);
}
__device__ __forceinline__ unsigned pack2(float a, float b) {
    return (unsigned)f2us(a) | ((unsigned)f2us(b) << 16);
}
__device__ __forceinline__ float ldw(const void* p, long i, int bf) {
    return bf ? us2f(((const unsigned short*)p)[i]) : ((const float*)p)[i];
}
__device__ __forceinline__ float lrelu(float x) { return x > 0.f ? x : NEG_SLOPE * x; }
__device__ __forceinline__ float wsum(float x) {
#pragma unroll
    for (int o = 32; o > 0; o >>= 1) x += __shfl_xor(x, o);
    return x;
}
__device__ __forceinline__ float wmaxr(float x) {
#pragma unroll
    for (int o = 32; o > 0; o >>= 1) x = fmaxf(x, __shfl_xor(x, o));
    return x;
}
__device__ __forceinline__ float pick4(float4 v, int h) {
    return h == 0 ? v.x : (h == 1 ? v.y : (h == 2 ? v.z : v.w));
}

// ---------- dtype sniff ----------
__global__ void detect_kernel(const float* __restrict__ x, int* __restrict__ flag) {
    float v = x[threadIdx.x];
    int bad = (!(v == v)) || (fabsf(v) > 1e6f);
    unsigned long long m = __ballot(bad);
    if (threadIdx.x == 0) flag[0] = (m != 0ull) ? 1 : 0;
}

__global__ __launch_bounds__(256) void zero_int_kernel(int* p, int n) {
    int i = blockIdx.x * 256 + threadIdx.x;
    if (i < n) p[i] = 0;
}

// ---------- CSR build: bucket partition (256 dst-nodes per bucket) ----------
// K1: per-tile LDS histogram -> global bucket counts (few global atomics)
__global__ __launch_bounds__(256) void bucket_hist_kernel(const int* __restrict__ dst, int E, int nb,
                                                          int* __restrict__ bucket_cnt) {
    __shared__ int hist[512];
    for (int i = threadIdx.x; i < nb; i += 256) hist[i] = 0;
    __syncthreads();
    const int base = blockIdx.x * 4096;
    const int end = min(base + 4096, E);
    for (int i = base + threadIdx.x; i < end; i += 256)
        atomicAdd(&hist[dst[i] >> 8], 1);
    __syncthreads();
    for (int i = threadIdx.x; i < nb; i += 256)
        if (hist[i]) atomicAdd(&bucket_cnt[i], hist[i]);
}

// K2: scan bucket counts -> bucket_base (csr segment starts), init cursors, row_ptr[N]
__global__ __launch_bounds__(512) void bucket_scan_kernel(const int* __restrict__ bucket_cnt,
                                                          int* __restrict__ bucket_base,
                                                          int* __restrict__ cursor,
                                                          int nb, int* __restrict__ row_ptr, int N) {
    __shared__ int sc[512];
    const int t = threadIdx.x;
    const int v = (t < nb) ? bucket_cnt[t] : 0;
    int x = v;
    sc[t] = x;
    __syncthreads();
    for (int o = 1; o < 512; o <<= 1) {
        const int y = (t >= o) ? sc[t - o] : 0;
        __syncthreads();
        x += y;
        sc[t] = x;
        __syncthreads();
    }
    if (t < nb) { bucket_base[t] = x - v; cursor[t] = x - v; }
    if (t == nb - 1) { bucket_base[nb] = x; row_ptr[N] = x; }
}

// K3: partition (dst,src) pairs into bucket-contiguous tmp with clustered writes
__global__ __launch_bounds__(256) void partition_kernel(const int* __restrict__ src, const int* __restrict__ dst,
                                                        int E, int nb, int* __restrict__ cursor,
                                                        unsigned long long* __restrict__ tmp) {
    __shared__ int hist[512];
    __shared__ int tbase[512];
    for (int i = threadIdx.x; i < nb; i += 256) hist[i] = 0;
    __syncthreads();
    const int base = blockIdx.x * 4096;
    const int end = min(base + 4096, E);
    int myd[16], mys[16], myr[16];
#pragma unroll
    for (int j = 0; j < 16; ++j) {
        const int i = base + threadIdx.x + j * 256;
        if (i < end) {
            const int d = dst[i];
            myd[j] = d;
            mys[j] = src[i];
            myr[j] = atomicAdd(&hist[d >> 8], 1);
        } else {
            myd[j] = -1;
        }
    }
    __syncthreads();
    for (int i = threadIdx.x; i < nb; i += 256) {
        const int hv = hist[i];
        tbase[i] = hv ? atomicAdd(&cursor[i], hv) : 0;
    }
    __syncthreads();
#pragma unroll
    for (int j = 0; j < 16; ++j) {
        if (myd[j] >= 0) {
            const int b = myd[j] >> 8;
            tmp[(size_t)tbase[b] + myr[j]] = ((unsigned long long)(unsigned)myd[j] << 32) | (unsigned)mys[j];
        }
    }
}

// K4: per-bucket counting sort in LDS -> coalesced csr write + row_ptr for the bucket's nodes
__global__ __launch_bounds__(256) void bucket_sort_kernel(const unsigned long long* __restrict__ tmp,
                                                          const int* __restrict__ bucket_base,
                                                          int* __restrict__ row_ptr, int* __restrict__ csr,
                                                          int N) {
    __shared__ int hist[256];
    __shared__ int sc[256];
    __shared__ int off[256];
    __shared__ int outb[SEG_CAP];
    const int b = blockIdx.x;
    const int node0 = b << 8;
    const int nn = min(256, N - node0);
    const int s0 = bucket_base[b], s1 = bucket_base[b + 1];
    const int cnt = s1 - s0;
    const int t = threadIdx.x;
    hist[t] = 0;
    __syncthreads();
    for (int i = s0 + t; i < s1; i += 256) {
        const int d = (int)(tmp[i] >> 32) - node0;
        atomicAdd(&hist[d], 1);
    }
    __syncthreads();
    const int v = hist[t];
    int x = v;
    sc[t] = x;
    __syncthreads();
    for (int o = 1; o < 256; o <<= 1) {
        const int y = (t >= o) ? sc[t - o] : 0;
        __syncthreads();
        x += y;
        sc[t] = x;
        __syncthreads();
    }
    off[t] = x - v;
    if (t < nn) row_ptr[node0 + t] = s0 + (x - v);
    hist[t] = 0;   // reuse as per-node cursors
    __syncthreads();
    if (cnt <= SEG_CAP) {
        for (int i = s0 + t; i < s1; i += 256) {
            const unsigned long long pr = tmp[i];
            const int d = (int)(pr >> 32) - node0;
            const int p = off[d] + atomicAdd(&hist[d], 1);
            outb[p] = (int)(unsigned)(pr & 0xffffffffu);
        }
        __syncthreads();
        for (int i = t; i < cnt; i += 256) csr[s0 + i] = outb[i];
    } else {  // overflow fallback (statistically unreachable)
        for (int i = s0 + t; i < s1; i += 256) {
            const unsigned long long pr = tmp[i];
            const int d = (int)(pr >> 32) - node0;
            const int p = off[d] + atomicAdd(&hist[d], 1);
            csr[s0 + p] = (int)(unsigned)(pr & 0xffffffffu);
        }
    }
}

// ---------- W transpose+convert: Wt[n][k] = bf16(W[w_off + k*128 + n]) ----------
__global__ __launch_bounds__(256) void transpose_w_kernel(const void* __restrict__ W, long w_off, int K,
                                                          unsigned short* __restrict__ Wt,
                                                          const int* __restrict__ flagp) {
    const int bf = flagp[0];
    const int i = blockIdx.x * 256 + threadIdx.x;
    if (i >= 128 * K) return;
    const int n = i / K, k = i - n * K;
    const long s = w_off + (long)k * 128 + n;
    Wt[i] = bf ? ((const unsigned short*)W)[s] : f2us(((const float*)W)[s]);
}

// ---------- MFMA GEMM: C[M,128] = act(A[M,K] @ B[K,128] + bias) ----------
template <int C_BF>
__global__ __launch_bounds__(256) void mfma_gemm_kernel(const void* __restrict__ Ap, int a_input,
                                                        const unsigned short* __restrict__ Bt,
                                                        const void* __restrict__ bias, long bias_off,
                                                        void* __restrict__ Cp,
                                                        int M, int K, int do_relu,
                                                        const int* __restrict__ flagp) {
    __shared__ unsigned short As[128 * 40];
    __shared__ unsigned short Bs[128 * 40];
    const int bf = flagp[0];
    const int a_bf = a_input ? bf : 2;  // 2 == fp32 workspace
    const int t = threadIdx.x;
    const int bm = blockIdx.x * 128;
    const int lane = t & 63, wave = t >> 6;
    const int r = lane & 15, quad = lane >> 4;
    const int srow = t >> 1, skh = (t & 1) * 16;

    floatx4 acc[2][8];
#pragma unroll
    for (int mt = 0; mt < 2; ++mt)
#pragma unroll
        for (int nt = 0; nt < 8; ++nt)
#pragma unroll
            for (int q = 0; q < 4; ++q) acc[mt][nt][q] = 0.f;

    for (int k0 = 0; k0 < K; k0 += 32) {
        {
            const int grow = bm + srow;
            uint4 u0 = make_uint4(0, 0, 0, 0), u1 = u0;
            if (grow < M) {
                const long aidx = (long)grow * K + k0 + skh;
                if (a_bf == 1) {
                    const unsigned short* ap = (const unsigned short*)Ap + aidx;
                    u0 = ((const uint4*)ap)[0];
                    u1 = ((const uint4*)ap)[1];
                } else {
                    const float* ap = (const float*)Ap + aidx;
                    float4 f0 = ((const float4*)ap)[0];
                    float4 f1 = ((const float4*)ap)[1];
                    float4 f2 = ((const float4*)ap)[2];
                    float4 f3 = ((const float4*)ap)[3];
                    u0 = make_uint4(pack2(f0.x, f0.y), pack2(f0.z, f0.w), pack2(f1.x, f1.y), pack2(f1.z, f1.w));
                    u1 = make_uint4(pack2(f2.x, f2.y), pack2(f2.z, f2.w), pack2(f3.x, f3.y), pack2(f3.z, f3.w));
                }
            }
            *(uint4*)&As[srow * 40 + skh]     = u0;
            *(uint4*)&As[srow * 40 + skh + 8] = u1;
        }
        {
            const unsigned short* bp = Bt + (long)srow * K + k0 + skh;
            uint4 v0 = ((const uint4*)bp)[0];
            uint4 v1 = ((const uint4*)bp)[1];
            *(uint4*)&Bs[srow * 40 + skh]     = v0;
            *(uint4*)&Bs[srow * 40 + skh + 8] = v1;
        }
        __syncthreads();

        short8 afr[2];
        afr[0] = *(const short8*)&As[(wave * 32 + r) * 40 + quad * 8];
        afr[1] = *(const short8*)&As[(wave * 32 + 16 + r) * 40 + quad * 8];
#pragma unroll
        for (int nt = 0; nt < 8; ++nt) {
            short8 bfr = *(const short8*)&Bs[(nt * 16 + r) * 40 + quad * 8];
            acc[0][nt] = __builtin_amdgcn_mfma_f32_16x16x32_bf16(afr[0], bfr, acc[0][nt], 0, 0, 0);
            acc[1][nt] = __builtin_amdgcn_mfma_f32_16x16x32_bf16(afr[1], bfr, acc[1][nt], 0, 0, 0);
        }
        __syncthreads();
    }

    float bb[8];
#pragma unroll
    for (int nt = 0; nt < 8; ++nt) bb[nt] = bias ? ldw(bias, bias_off + nt * 16 + r, bf) : 0.f;

#pragma unroll
    for (int mt = 0; mt < 2; ++mt) {
        const int gr0 = bm + wave * 32 + mt * 16 + quad * 4;
#pragma unroll
        for (int reg = 0; reg < 4; ++reg) {
            const int grow = gr0 + reg;
            if (grow < M) {
#pragma unroll
                for (int nt = 0; nt < 8; ++nt) {
                    float v = acc[mt][nt][reg] + bb[nt];
                    if (do_relu) v = fmaxf(v, 0.f);
                    const long ci = (long)grow * HID + nt * 16 + r;
                    if (C_BF) ((unsigned short*)Cp)[ci] = f2us(v);
                    else      ((float*)Cp)[ci] = v;
                }
            }
        }
    }
}

// ---------- per-node attention scalars ----------
__global__ __launch_bounds__(256) void attn_kernel(const unsigned short* __restrict__ hp,
                                                   const void* __restrict__ att_src,
                                                   const void* __restrict__ att_dst, long a_off,
                                                   float* __restrict__ asrc, float* __restrict__ adst,
                                                   int N, const int* __restrict__ flagp) {
    __shared__ float sA[128], sD[128];
    const int bf = flagp[0];
    const int t = threadIdx.x;
    if (t < 128) { sA[t] = ldw(att_src, a_off + t, bf); sD[t] = ldw(att_dst, a_off + t, bf); }
    __syncthreads();
    const int gid = blockIdx.x * 256 + t;
    if (gid >= N * 4) return;
    const int n = gid >> 2, hd = gid & 3;
    const unsigned short* p = hp + (size_t)n * HID + hd * 32;
    float s1 = 0.f, s2 = 0.f;
#pragma unroll
    for (int q = 0; q < 4; ++q) {
        uint4 v = ((const uint4*)p)[q];
        unsigned arr[4] = {v.x, v.y, v.z, v.w};
#pragma unroll
        for (int j = 0; j < 4; ++j) {
            const int k = q * 8 + j * 2;
            float lo = lo2f(arr[j]);
            float hi = hi2f(arr[j]);
            s1 += lo * sA[hd * 32 + k] + hi * sA[hd * 32 + k + 1];
            s2 += lo * sD[hd * 32 + k] + hi * sD[hd * 32 + k + 1];
        }
    }
    asrc[gid] = s1;
    adst[gid] = s2;
}

// ---------- GAT aggregate + bias + LN + ReLU + residual (one wave per dst node) ----------
__global__ __launch_bounds__(256) void gat_kernel(float* __restrict__ h,
                                                  const unsigned short* __restrict__ hp,
                                                  const float* __restrict__ asrc,
                                                  const float* __restrict__ adst,
                                                  const int* __restrict__ row_ptr,
                                                  const int* __restrict__ csr,
                                                  const void* __restrict__ bgat,
                                                  const void* __restrict__ lng,
                                                  const void* __restrict__ lnb, long w_off,
                                                  int N, const int* __restrict__ flagp) {
    __shared__ uint2 ebuf[4][320];
    const int bf = flagp[0];
    const int lane = threadIdx.x & 63;
    const int wslot = threadIdx.x >> 6;
    const int head = lane >> 4;
    const int n = (blockIdx.x << 2) | wslot;
    if (n >= N) return;

    const int e0 = row_ptr[n], e1 = row_ptr[n + 1];
    const int d = e1 - e0;
    const float4 ad4 = *(const float4*)(adst + (size_t)n * 4);
    const float4 as4 = *(const float4*)(asrc + (size_t)n * 4);
    float4 es;
    es.x = lrelu(as4.x + ad4.x); es.y = lrelu(as4.y + ad4.y);
    es.z = lrelu(as4.z + ad4.z); es.w = lrelu(as4.w + ad4.w);

    float2 acc;
    float4 dn, exs;
    const int l2 = lane * 2;

    if (d <= 64) {
        // ---- fast path ----
        int s = 0;
        float4 l4 = es;
        if (lane < d) {
            s = csr[e0 + lane];
            const float4 a = *(const float4*)(asrc + (size_t)s * 4);
            l4.x = lrelu(a.x + ad4.x);
            l4.y = lrelu(a.y + ad4.y);
            l4.z = lrelu(a.z + ad4.z);
            l4.w = lrelu(a.w + ad4.w);
        }
        float4 m;
        m.x = fmaxf(wmaxr(l4.x), es.x);
        m.y = fmaxf(wmaxr(l4.y), es.y);
        m.z = fmaxf(wmaxr(l4.z), es.z);
        m.w = fmaxf(wmaxr(l4.w), es.w);

        exs.x = expf(es.x - m.x); exs.y = expf(es.y - m.y);
        exs.z = expf(es.z - m.z); exs.w = expf(es.w - m.w);

        float4 ex4 = make_float4(0.f, 0.f, 0.f, 0.f);
        if (lane < d) {
            ex4.x = expf(l4.x - m.x);
            ex4.y = expf(l4.y - m.y);
            ex4.z = expf(l4.z - m.z);
            ex4.w = expf(l4.w - m.w);
        }
        dn.x = wsum(ex4.x) + exs.x;
        dn.y = wsum(ex4.y) + exs.y;
        dn.z = wsum(ex4.z) + exs.z;
        dn.w = wsum(ex4.w) + exs.w;

        uint2* eb = ebuf[wslot];
        const unsigned su = (unsigned)s;
        eb[lane * 5 + 0] = make_uint2(su, __float_as_uint(ex4.x));
        eb[lane * 5 + 1] = make_uint2(su, __float_as_uint(ex4.y));
        eb[lane * 5 + 2] = make_uint2(su, __float_as_uint(ex4.z));
        eb[lane * 5 + 3] = make_uint2(su, __float_as_uint(ex4.w));

        const float wself = pick4(exs, head);
        const unsigned hv0 = *(const unsigned*)(hp + (size_t)n * HID + l2);
        acc.x = wself * lo2f(hv0);
        acc.y = wself * hi2f(hv0);

        float2 a0 = {0.f, 0.f}, a1 = {0.f, 0.f}, a2 = {0.f, 0.f}, a3 = {0.f, 0.f};
        int i = 0;
        for (; i + 4 <= d; i += 4) {
            const uint2 q0 = eb[(i + 0) * 5 + head];
            const uint2 q1 = eb[(i + 1) * 5 + head];
            const uint2 q2 = eb[(i + 2) * 5 + head];
            const uint2 q3 = eb[(i + 3) * 5 + head];
            const unsigned u0 = *(const unsigned*)(hp + (size_t)q0.x * HID + l2);
            const unsigned u1 = *(const unsigned*)(hp + (size_t)q1.x * HID + l2);
            const unsigned u2 = *(const unsigned*)(hp + (size_t)q2.x * HID + l2);
            const unsigned u3 = *(const unsigned*)(hp + (size_t)q3.x * HID + l2);
            const float w0 = __uint_as_float(q0.y);
            const float w1 = __uint_as_float(q1.y);
            const float w2 = __uint_as_float(q2.y);
            const float w3 = __uint_as_float(q3.y);
            a0.x = fmaf(w0, lo2f(u0), a0.x); a0.y = fmaf(w0, hi2f(u0), a0.y);
            a1.x = fmaf(w1, lo2f(u1), a1.x); a1.y = fmaf(w1, hi2f(u1), a1.y);
            a2.x = fmaf(w2, lo2f(u2), a2.x); a2.y = fmaf(w2, hi2f(u2), a2.y);
            a3.x = fmaf(w3, lo2f(u3), a3.x); a3.y = fmaf(w3, hi2f(u3), a3.y);
        }
        for (; i < d; ++i) {
            const uint2 q = eb[i * 5 + head];
            const unsigned u = *(const unsigned*)(hp + (size_t)q.x * HID + l2);
            const float wq = __uint_as_float(q.y);
            acc.x = fmaf(wq, lo2f(u), acc.x);
            acc.y = fmaf(wq, hi2f(u), acc.y);
        }
        acc.x += (a0.x + a1.x) + (a2.x + a3.x);
        acc.y += (a0.y + a1.y) + (a2.y + a3.y);
    } else {
        // ---- slow path (deg > 64) ----
        float4 m = es;
        for (int e = e0 + lane; e < e1; e += 64) {
            const int s = csr[e];
            const float4 a = *(const float4*)(asrc + (size_t)s * 4);
            m.x = fmaxf(m.x, lrelu(a.x + ad4.x));
            m.y = fmaxf(m.y, lrelu(a.y + ad4.y));
            m.z = fmaxf(m.z, lrelu(a.z + ad4.z));
            m.w = fmaxf(m.w, lrelu(a.w + ad4.w));
        }
        m.x = wmaxr(m.x); m.y = wmaxr(m.y); m.z = wmaxr(m.z); m.w = wmaxr(m.w);

        exs.x = expf(es.x - m.x); exs.y = expf(es.y - m.y);
        exs.z = expf(es.z - m.z); exs.w = expf(es.w - m.w);

        const float wself = pick4(exs, head);
        const unsigned hv0 = *(const unsigned*)(hp + (size_t)n * HID + l2);
        acc.x = wself * lo2f(hv0);
        acc.y = wself * hi2f(hv0);
        dn = make_float4(0.f, 0.f, 0.f, 0.f);

        for (int base = e0; base < e1; base += 64) {
            const int cnt = min(64, e1 - base);
            int s = 0;
            float4 ex4 = make_float4(0.f, 0.f, 0.f, 0.f);
            if (base + lane < e1) {
                s = csr[base + lane];
                const float4 a = *(const float4*)(asrc + (size_t)s * 4);
                ex4.x = expf(lrelu(a.x + ad4.x) - m.x);
                ex4.y = expf(lrelu(a.y + ad4.y) - m.y);
                ex4.z = expf(lrelu(a.z + ad4.z) - m.z);
                ex4.w = expf(lrelu(a.w + ad4.w) - m.w);
                dn.x += ex4.x; dn.y += ex4.y; dn.z += ex4.z; dn.w += ex4.w;
            }
            for (int i = 0; i < cnt; ++i) {
                const int ss = __shfl(s, i);
                const float wx = __shfl(ex4.x, i);
                const float wy = __shfl(ex4.y, i);
                const float wz = __shfl(ex4.z, i);
                const float ww = __shfl(ex4.w, i);
                const float wgt = head == 0 ? wx : (head == 1 ? wy : (head == 2 ? wz : ww));
                const unsigned uv = *(const unsigned*)(hp + (size_t)ss * HID + l2);
                acc.x = fmaf(wgt, lo2f(uv), acc.x);
                acc.y = fmaf(wgt, hi2f(uv), acc.y);
            }
        }
        dn.x = wsum(dn.x) + exs.x;
        dn.y = wsum(dn.y) + exs.y;
        dn.z = wsum(dn.z) + exs.z;
        dn.w = wsum(dn.w) + exs.w;
    }

    const float invd = 1.f / fmaxf(pick4(dn, head), 1e-16f);
    acc.x *= invd; acc.y *= invd;
    acc.x += ldw(bgat, w_off + l2, bf);
    acc.y += ldw(bgat, w_off + l2 + 1, bf);

    float mean = wsum(acc.x + acc.y) * (1.f / 128.f);
    float dx = acc.x - mean, dy = acc.y - mean;
    float var = wsum(dx * dx + dy * dy) * (1.f / 128.f);
    float rstd = rsqrtf(var + LN_EPS);
    float o0 = dx * rstd * ldw(lng, w_off + l2, bf)     + ldw(lnb, w_off + l2, bf);
    float o1 = dy * rstd * ldw(lng, w_off + l2 + 1, bf) + ldw(lnb, w_off + l2 + 1, bf);
    o0 = fmaxf(o0, 0.f);
    o1 = fmaxf(o1, 0.f);

    const float2 r = *(const float2*)(h + (size_t)n * HID + l2);
    *(float2*)(h + (size_t)n * HID + l2) = make_float2(o0 + r.x, o1 + r.y);
}

// ---------- pooling (sorted batch -> contiguous ranges, no atomics) ----------
__global__ __launch_bounds__(256) void pool_kernel(const float* __restrict__ h, const int* __restrict__ batch,
                                                   void* __restrict__ out, int N,
                                                   const int* __restrict__ flagp) {
    const int g = blockIdx.x;
    int a = 0, b = N;
    while (a < b) { int mid = (a + b) >> 1; if (batch[mid] < g) a = mid + 1; else b = mid; }
    const int lo = a;
    b = N;
    while (a < b) { int mid = (a + b) >> 1; if (batch[mid] <= g) a = mid + 1; else b = mid; }
    const int hi = a;

    const int col = threadIdx.x & 127;
    const int half = threadIdx.x >> 7;
    float s = 0.f;
    for (int r = lo + half; r < hi; r += 2) s += h[(size_t)r * HID + col];
    __shared__ float part[128];
    if (half == 0) part[col] = s;
    __syncthreads();
    if (half == 1) {
        const float tot = part[col] + s;
        const float v = tot / fmaxf((float)(hi - lo), 1.f);
        if (flagp[0]) ((unsigned short*)out)[g * HID + col] = f2us(v);
        else          ((float*)out)[g * HID + col] = v;
    }
}

// ---------- launch ----------
extern "C" void kernel_launch(void* const* d_in, const int* in_sizes, int n_in,
                              void* d_out, int out_size, void* d_ws, size_t ws_size,
                              hipStream_t stream) {
    const void* x     = d_in[0];
    const void* W_in  = d_in[1];
    const void* b_in  = d_in[2];
    const void* W_gat = d_in[3];
    const void* att_s = d_in[4];
    const void* att_d = d_in[5];
    const void* b_gat = d_in[6];
    const void* ln_g  = d_in[7];
    const void* ln_b  = d_in[8];
    const int* edge_index = (const int*)d_in[9];
    const int* batch      = (const int*)d_in[10];

    const int N = in_sizes[10];
    const int E = in_sizes[9] / 2;
    const int IN_DIM = in_sizes[0] / N;
    const int n_graphs = out_size / HID;

    const int* esrc = edge_index;
    const int* edst = edge_index + E;

    char* w = (char*)d_ws;
    auto carve = [&](size_t bytes) -> void* {
        void* p = (void*)w;
        w += (bytes + 255) & ~(size_t)255;
        return p;
    };
    int* flag             = (int*)carve(256);
    int* row_ptr          = (int*)carve((size_t)(N + 1) * 4);
    int* csr              = (int*)carve((size_t)E * 4);
    float* asrc           = (float*)carve((size_t)N * 4 * 4);
    float* adst           = (float*)carve((size_t)N * 4 * 4);
    int* bucket_cnt       = (int*)carve(512 * 4);
    int* bucket_base      = (int*)carve(513 * 4);
    int* cursor           = (int*)carve(512 * 4);
    unsigned short* Wt_in = (unsigned short*)carve((size_t)HID * IN_DIM * 2);
    unsigned short* Wt_g  = (unsigned short*)carve((size_t)HID * HID * 2);
    float* h              = (float*)carve((size_t)N * HID * 4);
    unsigned short* hp    = (unsigned short*)carve((size_t)N * HID * 2);
    // tmp (E x 8B) aliases h: only live during CSR build, before h is first written
    unsigned long long* tmp = (unsigned long long*)h;
    (void)ws_size; (void)n_in;

    detect_kernel<<<1, 64, 0, stream>>>((const float*)x, flag);

    // CSR build via bucket partition (256 dst-nodes per bucket)
    const int nb = (N + 255) >> 8;
    const int ntiles = (E + 4095) / 4096;
    zero_int_kernel<<<2, 256, 0, stream>>>(bucket_cnt, 512);
    bucket_hist_kernel<<<ntiles, 256, 0, stream>>>(edst, E, nb, bucket_cnt);
    bucket_scan_kernel<<<1, 512, 0, stream>>>(bucket_cnt, bucket_base, cursor, nb, row_ptr, N);
    partition_kernel<<<ntiles, 256, 0, stream>>>(esrc, edst, E, nb, cursor, tmp);
    bucket_sort_kernel<<<nb, 256, 0, stream>>>(tmp, bucket_base, row_ptr, csr, N);

    // input projection: h = relu(x @ W_in + b_in)
    transpose_w_kernel<<<(HID * IN_DIM + 255) / 256, 256, 0, stream>>>(W_in, 0, IN_DIM, Wt_in, flag);
    mfma_gemm_kernel<0><<<(N + 127) / 128, 256, 0, stream>>>(x, 1, Wt_in, b_in, 0, h, N, IN_DIM, 1, flag);

    for (int l = 0; l < 3; ++l) {
        transpose_w_kernel<<<(HID * HID + 255) / 256, 256, 0, stream>>>(W_gat, (long)l * HID * HID, HID, Wt_g, flag);
        mfma_gemm_kernel<1><<<(N + 127) / 128, 256, 0, stream>>>(h, 0, Wt_g, nullptr, 0, hp, N, HID, 0, flag);
        attn_kernel<<<(N * 4 + 255) / 256, 256, 0, stream>>>(hp, att_s, att_d, (long)l * HID,
                                                             asrc, adst, N, flag);
        gat_kernel<<<(N + 3) / 4, 256, 0, stream>>>(h, hp, asrc, adst, row_ptr, csr,
                                                    b_gat, ln_g, ln_b, (long)l * HID, N, flag);
    }

    pool_kernel<<<n_graphs, 256, 0, stream>>>(h, batch, d_out, N, flag);
}